// Round 2
// baseline (1068.066 us; speedup 1.0000x reference)
//
#include <hip/hip_runtime.h>
#include <hip/hip_bf16.h>

typedef __hip_bfloat16 bf16;

__device__ __forceinline__ float b2f(bf16 v){ return __bfloat162float(v); }
__device__ __forceinline__ bf16  f2b(float v){ return __float2bfloat16(v); }
__device__ __forceinline__ float toF(float v){ return v; }
__device__ __forceinline__ float toF(bf16 v){ return b2f(v); }

#define NTOK 1024  // H*W = 32*32 token positions per batch

// ---------- generic channel-major GEMM: Y[z][o][n] = act(sum_k W[o][k] * X[z][k][n]) ----------
// ACT: 0=none, 1=relu, 2=(1-sigmoid). W is f32 row-major [O][K]; X is TX; Y f32.
template<typename TX, int ACT, int OGRP>
__global__ __launch_bounds__(256) void gemm_cm(const float* __restrict__ W,
                                               const TX* __restrict__ X,
                                               float* __restrict__ Y,
                                               int K, long ldxz, long ldyz) {
  int n  = blockIdx.x * 256 + threadIdx.x;   // 0..1023
  int o0 = blockIdx.y * OGRP;
  long z = blockIdx.z;
  const TX* Xp = X + z * ldxz + n;
  const float* Wp = W + (long)o0 * K;
  float acc[OGRP];
#pragma unroll
  for (int i = 0; i < OGRP; ++i) acc[i] = 0.f;
#pragma unroll 4
  for (int k = 0; k < K; ++k) {
    float x = toF(Xp[(long)k * NTOK]);
#pragma unroll
    for (int i = 0; i < OGRP; ++i) acc[i] = fmaf(Wp[i * K + k], x, acc[i]);
  }
  float* Yp = Y + z * ldyz + (long)o0 * NTOK + n;
#pragma unroll
  for (int i = 0; i < OGRP; ++i) {
    float v = acc[i];
    if (ACT == 1) v = fmaxf(v, 0.f);
    else if (ACT == 2) v = 1.f / (1.f + __expf(v));   // 1 - sigmoid(v)
    Yp[(long)i * NTOK] = v;
  }
}

// ---------- fused 2-layer token MLP with unfold gather ----------
// E[z][o][n] = (relu(X @ W1^T) @ W2^T), X[k][n] = V[b, k, hn*R+dy, wn*R+dx]
// z = b*R*R + p; block = one z-slice x 256-token tile. LDS: X tile + hidden tile.
template<int K, int R>
__global__ __launch_bounds__(256) void mlp_fused(const float* __restrict__ W1,  // [128][K]
                                                 const float* __restrict__ W2,  // [128][128]
                                                 const float* __restrict__ V,   // f32
                                                 bf16* __restrict__ E,          // [z][128][1024]
                                                 int HW) {
  __shared__ bf16 xs[K][256];
  __shared__ bf16 hs[128][256];
  int t = threadIdx.x;
  int n0 = blockIdx.x * 256;
  int z = blockIdx.y;
  const int P = R * R;
  int p = z % P, b = z / P;
  int dy = p / R, dx = p % R;
  // stage X tile (strided gather)
  for (int idx = t; idx < K * 256; idx += 256) {
    int k = idx >> 8, j = idx & 255;
    int n = n0 + j;
    int hn = n >> 5, wn = n & 31;
    xs[k][j] = f2b(V[((long)(b * K + k) * HW + hn * R + dy) * HW + wn * R + dx]);
  }
  __syncthreads();
  // layer 1: each thread owns token column t; 16 groups of 8 channels
  for (int og = 0; og < 16; ++og) {
    const float* Wp = W1 + og * 8 * K;
    float acc[8] = {0,0,0,0,0,0,0,0};
#pragma unroll 4
    for (int k = 0; k < K; ++k) {
      float x = b2f(xs[k][t]);
#pragma unroll
      for (int i = 0; i < 8; ++i) acc[i] = fmaf(Wp[i * K + k], x, acc[i]);
    }
#pragma unroll
    for (int i = 0; i < 8; ++i) hs[og * 8 + i][t] = f2b(fmaxf(acc[i], 0.f));
  }
  __syncthreads();
  // layer 2
  for (int og = 0; og < 16; ++og) {
    const float* Wp = W2 + og * 8 * 128;
    float acc[8] = {0,0,0,0,0,0,0,0};
#pragma unroll 4
    for (int k = 0; k < 128; ++k) {
      float x = b2f(hs[k][t]);
#pragma unroll
      for (int i = 0; i < 8; ++i) acc[i] = fmaf(Wp[i * 128 + k], x, acc[i]);
    }
#pragma unroll
    for (int i = 0; i < 8; ++i)
      E[((long)z * 128 + og * 8 + i) * NTOK + n0 + t] = f2b(acc[i]);
  }
}

// ---------- attention score: S[z][n] = sum_c E[z][c][n] * w[c]  (c = 128) ----------
template<typename TE>
__global__ __launch_bounds__(256) void score_k(const TE* __restrict__ E,
                                               const float* __restrict__ w,
                                               float* __restrict__ S) {
  int n = blockIdx.x * 256 + threadIdx.x;
  long z = blockIdx.y;
  const TE* Ep = E + z * (128l * NTOK) + n;
  float s = 0.f;
#pragma unroll 4
  for (int c = 0; c < 128; ++c) s = fmaf(toF(Ep[(long)c * NTOK]), w[c], s);
  S[z * NTOK + n] = s;
}

// ---------- softmax over P patch positions: score = relu(sa + sb) then softmax ----------
template<int P>
__global__ __launch_bounds__(256) void softmax_k(const float* __restrict__ SA,
                                                 const float* __restrict__ SB,
                                                 float* __restrict__ ATT) {
  int i = blockIdx.x * 256 + threadIdx.x;  // over B*NTOK = 8192
  int b = i >> 10, n = i & 1023;
  float sa = SA[(long)b * NTOK + n];
  float s[P];
  float m = 0.f;  // scores >= 0 after relu
#pragma unroll
  for (int p = 0; p < P; ++p) {
    s[p] = fmaxf(sa + SB[((long)b * P + p) * NTOK + n], 0.f);
    m = fmaxf(m, s[p]);
  }
  float den = 0.f;
#pragma unroll
  for (int p = 0; p < P; ++p) { s[p] = __expf(s[p] - m); den += s[p]; }
  float r = 1.f / den;
#pragma unroll
  for (int p = 0; p < P; ++p) ATT[((long)b * P + p) * NTOK + n] = s[p] * r;
}

// ---------- feat = sigmoid(concat(gate_b*agg_b, gate_c*agg_c, emb_a)) -> bf16 ----------
__global__ __launch_bounds__(256) void feat_k(const bf16* __restrict__ emb_b,
                                              const bf16* __restrict__ emb_c,
                                              const float* __restrict__ emb_a,
                                              const float* __restrict__ gate_b,
                                              const float* __restrict__ gate_c,
                                              const float* __restrict__ attn_b,
                                              const float* __restrict__ attn_c,
                                              bf16* __restrict__ feat) {
  int n = blockIdx.x * 256 + threadIdx.x;
  int c = blockIdx.y;   // 0..383
  int b = blockIdx.z;
  float v;
  if (c < 128) {
    float s = 0.f;
#pragma unroll
    for (int p = 0; p < 4; ++p)
      s = fmaf(b2f(emb_b[(((long)b * 4 + p) * 128 + c) * NTOK + n]),
               attn_b[((long)b * 4 + p) * NTOK + n], s);
    v = s * gate_b[((long)b * 128 + c) * NTOK + n];
  } else if (c < 256) {
    int cc = c - 128;
    float s = 0.f;
#pragma unroll
    for (int p = 0; p < 16; ++p)
      s = fmaf(b2f(emb_c[(((long)b * 16 + p) * 128 + cc) * NTOK + n]),
               attn_c[((long)b * 16 + p) * NTOK + n], s);
    v = s * gate_c[((long)b * 128 + cc) * NTOK + n];
  } else {
    v = emb_a[((long)b * 128 + (c - 256)) * NTOK + n];
  }
  v = 1.f / (1.f + __expf(-v));
  feat[((long)b * 384 + c) * NTOK + n] = f2b(v);
}

extern "C" void kernel_launch(void* const* d_in, const int* in_sizes, int n_in,
                              void* d_out, int out_size, void* d_ws, size_t ws_size,
                              hipStream_t stream) {
  const float* vert_a = (const float*)d_in[0];   // (8,256,32,32)
  const float* vert_b = (const float*)d_in[1];   // (8,128,64,64)
  const float* vert_c = (const float*)d_in[2];   // (8,64,128,128)
  const float* Wa1 = (const float*)d_in[3];
  const float* Wa2 = (const float*)d_in[4];
  const float* Wgb = (const float*)d_in[5];
  const float* Wgc = (const float*)d_in[6];
  const float* Wb1 = (const float*)d_in[7];
  const float* Wb2 = (const float*)d_in[8];
  const float* Wc1 = (const float*)d_in[9];
  const float* Wc2 = (const float*)d_in[10];
  const float* wab = (const float*)d_in[11];
  const float* wac = (const float*)d_in[12];
  const float* Wr1 = (const float*)d_in[13];
  const float* Wr2 = (const float*)d_in[14];

  char* wsb = (char*)d_ws;
  size_t off = 0;
  float* h_buf  = (float*)(wsb + off); off += (size_t)8*256*1024*4;   // hidden_a / h_r (8 MB)
  float* emb_a  = (float*)(wsb + off); off += (size_t)8*128*1024*4;   // 4 MB
  float* gate_b = (float*)(wsb + off); off += (size_t)8*128*1024*4;   // 4 MB
  float* gate_c = (float*)(wsb + off); off += (size_t)8*128*1024*4;   // 4 MB
  bf16*  emb_b  = (bf16*)(wsb + off);  off += (size_t)32*128*1024*2;  // 8 MB
  bf16*  emb_c  = (bf16*)(wsb + off);  off += (size_t)128*128*1024*2; // 32 MB
  bf16*  feat   = (bf16*)(wsb + off);  off += (size_t)8*384*1024*2;   // 6 MB
  float* sa_b   = (float*)(wsb + off); off += 8192*4;
  float* sb_b   = (float*)(wsb + off); off += 32768*4;
  float* sa_c   = (float*)(wsb + off); off += 8192*4;
  float* sb_c   = (float*)(wsb + off); off += 131072*4;
  float* attn_b = (float*)(wsb + off); off += 32768*4;
  float* attn_c = (float*)(wsb + off); off += 131072*4;   // total ~67 MB

  dim3 blk(256);
  // a-path: hidden_a = relu(Wa1@va); emb_a = Wa2@hidden; gates = 1-sigmoid(Wg@va)
  gemm_cm<float,1,8><<<dim3(4,16,8), blk, 0, stream>>>(Wa1, vert_a, h_buf, 256, 256l*NTOK, 128l*NTOK);
  gemm_cm<float,0,8><<<dim3(4,16,8), blk, 0, stream>>>(Wa2, h_buf, emb_a, 128, 128l*NTOK, 128l*NTOK);
  gemm_cm<float,2,8><<<dim3(4,16,8), blk, 0, stream>>>(Wgb, vert_a, gate_b, 256, 256l*NTOK, 128l*NTOK);
  gemm_cm<float,2,8><<<dim3(4,16,8), blk, 0, stream>>>(Wgc, vert_a, gate_c, 256, 256l*NTOK, 128l*NTOK);
  // token MLPs (fused 2 layers + unfold)
  mlp_fused<128,2><<<dim3(4,32),  blk, 0, stream>>>(Wb1, Wb2, vert_b, emb_b, 64);
  mlp_fused<64,4> <<<dim3(4,128), blk, 0, stream>>>(Wc1, Wc2, vert_c, emb_c, 128);
  // attention scores
  score_k<float><<<dim3(4,8),   blk, 0, stream>>>(emb_a, wab,       sa_b);
  score_k<bf16> <<<dim3(4,32),  blk, 0, stream>>>(emb_b, wab + 128, sb_b);
  score_k<float><<<dim3(4,8),   blk, 0, stream>>>(emb_a, wac,       sa_c);
  score_k<bf16> <<<dim3(4,128), blk, 0, stream>>>(emb_c, wac + 128, sb_c);
  // softmax over patch positions
  softmax_k<4> <<<32, blk, 0, stream>>>(sa_b, sb_b, attn_b);
  softmax_k<16><<<32, blk, 0, stream>>>(sa_c, sb_c, attn_c);
  // feat = sigmoid([agg_b*gate_b ; agg_c*gate_c ; emb_a])
  feat_k<<<dim3(4,384,8), blk, 0, stream>>>(emb_b, emb_c, emb_a, gate_b, gate_c,
                                            attn_b, attn_c, feat);
  // readout: h_r = relu(Wr1@feat); out = Wr2@h_r
  gemm_cm<bf16,1,8> <<<dim3(4,32,8), blk, 0, stream>>>(Wr1, feat, h_buf, 384, 384l*NTOK, 256l*NTOK);
  gemm_cm<float,0,8><<<dim3(4,32,8), blk, 0, stream>>>(Wr2, h_buf, (float*)d_out, 256, 256l*NTOK, 256l*NTOK);
}

// Round 3
// 266.265 us; speedup vs baseline: 4.0113x; 4.0113x over previous
//
#include <hip/hip_runtime.h>
#include <hip/hip_bf16.h>

typedef __hip_bfloat16 bf16;
typedef __attribute__((ext_vector_type(8))) short v8s;   // 8 bf16 = 4 VGPRs (MFMA A/B frag)
typedef __attribute__((ext_vector_type(4))) float v4f;   // MFMA C/D frag

__device__ __forceinline__ float b2f(bf16 v){ return __bfloat162float(v); }
__device__ __forceinline__ short f2s(float v){ bf16 h = __float2bfloat16(v); return *(short*)&h; }
__device__ __forceinline__ float s2f(short s){ bf16 h = *(bf16*)&s; return b2f(h); }

#define NTOK 1024

// bf16 weight arena offsets (elements)
enum : int {
  OB_ABC = 0,                 // [384][256]: rows 0-127 Wa1, 128-255 Wgb, 256-383 Wgc
  OB_A2  = 98304,             // [128][128]
  OB_B1  = 114688,            // [128][128]
  OB_B2  = 131072,            // [128][128]
  OB_C1  = 147456,            // [128][64]
  OB_C2  = 155648,            // [128][128]
  OB_R1  = 172032,            // [256][384]
  OB_R2  = 270336,            // [256][256]
  OB_END = 335872
};

struct WSeg { const float* src; int off; int n; };
struct WPack { WSeg seg[10]; };

__global__ __launch_bounds__(256) void cvt_w(WPack P, short* __restrict__ wb) {
  WSeg s = P.seg[blockIdx.y];
  for (int i = blockIdx.x * 256 + threadIdx.x; i < s.n; i += gridDim.x * 256)
    wb[s.off + i] = f2s(s.src[i]);
}

__global__ __launch_bounds__(256) void cvt_f2b(const float* __restrict__ src,
                                               short* __restrict__ dst, int n) {
  int i = blockIdx.x * 256 + threadIdx.x;
  if (i < n) dst[i] = f2s(src[i]);
}

// tokenize unfold: T[(b*R*R+p)][k][n] = V[b][k][hn*R+dy][wn*R+dx], p=dy*R+dx, n=hn*32+wn
template<int R, int K>
__global__ __launch_bounds__(256) void tok_k(const float* __restrict__ V,
                                             short* __restrict__ T, int HW) {
  long i = (long)blockIdx.x * 256 + threadIdx.x;
  int n = i & 1023;
  long zk = i >> 10;
  int k = (int)(zk % K);
  int z = (int)(zk / K);
  int p = z % (R * R), b = z / (R * R);
  int dy = p / R, dx = p % R;
  int hn = n >> 5, wn = n & 31;
  T[i] = f2s(V[((long)(b * K + k) * HW + hn * R + dy) * HW + wn * R + dx]);
}

// ---------------- MFMA GEMM ----------------
// Y[z][o][n] = act( sum_k W[o][k] * X[z][k][n] ), all bf16 in, f32 acc.
// grid (N/128, M/128, z), block 256 (4 waves, 2x2 of 64x64 per wave).
// ACT: 0 none, 1 relu, 3 mixed (o<128 ? relu : 1-sigmoid)
template<int ACT, typename TOUT>
__global__ __launch_bounds__(256) void mfma_gemm(const short* __restrict__ W,  // [M][K]
                                                 const short* __restrict__ X,  // [z][K][1024]
                                                 TOUT* __restrict__ Y,         // [z][M][1024]
                                                 int K, long ldxz, long ldyz) {
  __shared__ __align__(16) short As[8192];  // [128 m][64 k], xor-swizzled
  __shared__ __align__(16) short Bs[8192];  // [128 n][64 k], xor-swizzled
  const int t = threadIdx.x;
  const int bn0 = blockIdx.x * 128;
  const int bm0 = blockIdx.y * 128;
  const long z = blockIdx.z;
  const short* Xz = X + z * ldxz;

  const int l = t & 63, w = t >> 6;
  const int wr = w >> 1, wc = w & 1;        // wave tile (64m x 64n)
  const int lr = l & 15, lk = (l >> 4) * 8; // frag row / k-offset

  v4f acc[4][4];
#pragma unroll
  for (int i = 0; i < 4; ++i)
#pragma unroll
    for (int j = 0; j < 4; ++j) acc[i][j] = (v4f){0.f, 0.f, 0.f, 0.f};

  const int ar = t >> 1, akh = (t & 1) * 32;     // A staging: row, k-half
  const int bn = t & 127, bkh = (t >> 7) * 32;   // B staging: n, k-half

  for (int k0 = 0; k0 < K; k0 += 64) {
    if (k0) __syncthreads();
    // stage A = W tile (row-major, 16B vector loads)
    const short* wrow = W + (long)(bm0 + ar) * K + k0 + akh;
#pragma unroll
    for (int c = 0; c < 4; ++c) {
      v8s pk = *(const v8s*)(wrow + 8 * c);
      *(v8s*)&As[(ar * 64 + akh + 8 * c) ^ ((ar & 7) << 3)] = pk;
    }
    // stage B = X^T tile (gather 8 k per n, coalesced across lanes in n)
    const short* xcol = Xz + (long)(k0 + bkh) * NTOK + bn0 + bn;
#pragma unroll
    for (int c = 0; c < 4; ++c) {
      v8s pk;
#pragma unroll
      for (int j = 0; j < 8; ++j) pk[j] = xcol[(long)(8 * c + j) * NTOK];
      *(v8s*)&Bs[(bn * 64 + bkh + 8 * c) ^ ((bn & 7) << 3)] = pk;
    }
    __syncthreads();
#pragma unroll
    for (int ks = 0; ks < 2; ++ks) {
      v8s af[4], bfr[4];
#pragma unroll
      for (int mi = 0; mi < 4; ++mi) {
        int row = wr * 64 + mi * 16 + lr;
        af[mi] = *(const v8s*)&As[(row * 64 + ks * 32 + lk) ^ ((row & 7) << 3)];
      }
#pragma unroll
      for (int ni = 0; ni < 4; ++ni) {
        int row = wc * 64 + ni * 16 + lr;
        bfr[ni] = *(const v8s*)&Bs[(row * 64 + ks * 32 + lk) ^ ((row & 7) << 3)];
      }
#pragma unroll
      for (int mi = 0; mi < 4; ++mi)
#pragma unroll
        for (int ni = 0; ni < 4; ++ni)
          acc[mi][ni] = __builtin_amdgcn_mfma_f32_16x16x32_bf16(af[mi], bfr[ni], acc[mi][ni], 0, 0, 0);
    }
  }
  // epilogue: D lane mapping col=l&15, row=(l>>4)*4+r
  const int ro = (l >> 4) * 4;
#pragma unroll
  for (int mi = 0; mi < 4; ++mi)
#pragma unroll
    for (int ni = 0; ni < 4; ++ni)
#pragma unroll
      for (int r = 0; r < 4; ++r) {
        int o = bm0 + wr * 64 + mi * 16 + ro + r;
        int n = bn0 + wc * 64 + ni * 16 + lr;
        float v = acc[mi][ni][r];
        if (ACT == 1) v = fmaxf(v, 0.f);
        else if (ACT == 3) v = (o < 128) ? fmaxf(v, 0.f) : 1.f / (1.f + __expf(v));
        if constexpr (sizeof(TOUT) == 4) Y[z * ldyz + (long)o * NTOK + n] = v;
        else Y[z * ldyz + (long)o * NTOK + n] = (TOUT)f2s(v);
      }
}

// score: S[z][n] = sum_c E[z][c][n]*w[c]
__global__ __launch_bounds__(256) void score_k(const short* __restrict__ E,
                                               const float* __restrict__ w,
                                               float* __restrict__ S) {
  int n = blockIdx.x * 256 + threadIdx.x;
  long z = blockIdx.y;
  const short* Ep = E + z * (128l * NTOK) + n;
  float s = 0.f;
#pragma unroll 4
  for (int c = 0; c < 128; ++c) s = fmaf(s2f(Ep[(long)c * NTOK]), w[c], s);
  S[z * NTOK + n] = s;
}

template<int P>
__global__ __launch_bounds__(256) void softmax_k(const float* __restrict__ SA,
                                                 const float* __restrict__ SB,
                                                 float* __restrict__ ATT) {
  int i = blockIdx.x * 256 + threadIdx.x;
  int b = i >> 10, n = i & 1023;
  float sa = SA[(long)b * NTOK + n];
  float s[P];
  float m = 0.f;
#pragma unroll
  for (int p = 0; p < P; ++p) {
    s[p] = fmaxf(sa + SB[((long)b * P + p) * NTOK + n], 0.f);
    m = fmaxf(m, s[p]);
  }
  float den = 0.f;
#pragma unroll
  for (int p = 0; p < P; ++p) { s[p] = __expf(s[p] - m); den += s[p]; }
  float r = 1.f / den;
#pragma unroll
  for (int p = 0; p < P; ++p) ATT[((long)b * P + p) * NTOK + n] = s[p] * r;
}

// feat = sigmoid([agg_b*gate_b ; agg_c*gate_c ; emb_a]); gates live in abc rows 128..384
__global__ __launch_bounds__(256) void feat_k(const short* __restrict__ emb_b,
                                              const short* __restrict__ emb_c,
                                              const short* __restrict__ emb_a,
                                              const short* __restrict__ abc,
                                              const float* __restrict__ attn_b,
                                              const float* __restrict__ attn_c,
                                              short* __restrict__ feat) {
  int n = blockIdx.x * 256 + threadIdx.x;
  int c = blockIdx.y;   // 0..383
  int b = blockIdx.z;
  float v;
  if (c < 128) {
    float s = 0.f;
#pragma unroll
    for (int p = 0; p < 4; ++p)
      s = fmaf(s2f(emb_b[(((long)b * 4 + p) * 128 + c) * NTOK + n]),
               attn_b[((long)b * 4 + p) * NTOK + n], s);
    v = s * s2f(abc[((long)b * 384 + 128 + c) * NTOK + n]);
  } else if (c < 256) {
    int cc = c - 128;
    float s = 0.f;
#pragma unroll
    for (int p = 0; p < 16; ++p)
      s = fmaf(s2f(emb_c[(((long)b * 16 + p) * 128 + cc) * NTOK + n]),
               attn_c[((long)b * 16 + p) * NTOK + n], s);
    v = s * s2f(abc[((long)b * 384 + 256 + cc) * NTOK + n]);
  } else {
    v = s2f(emb_a[((long)b * 128 + (c - 256)) * NTOK + n]);
  }
  v = 1.f / (1.f + __expf(-v));
  feat[((long)b * 384 + c) * NTOK + n] = f2s(v);
}

extern "C" void kernel_launch(void* const* d_in, const int* in_sizes, int n_in,
                              void* d_out, int out_size, void* d_ws, size_t ws_size,
                              hipStream_t stream) {
  const float* vert_a = (const float*)d_in[0];
  const float* vert_b = (const float*)d_in[1];
  const float* vert_c = (const float*)d_in[2];
  const float* wab = (const float*)d_in[11];
  const float* wac = (const float*)d_in[12];

  char* wsb = (char*)d_ws;
  size_t off = 0;
  auto alloc = [&](size_t bytes) { char* p = wsb + off; off += (bytes + 255) & ~(size_t)255; return p; };
  short* wb     = (short*)alloc(OB_END * 2);
  float* sa_b   = (float*)alloc(8192 * 4);
  float* sb_b   = (float*)alloc(32768 * 4);
  float* sa_c   = (float*)alloc(8192 * 4);
  float* sb_c   = (float*)alloc(131072 * 4);
  float* attn_b = (float*)alloc(32768 * 4);
  float* attn_c = (float*)alloc(131072 * 4);
  short* emb_a  = (short*)alloc((size_t)8 * 128 * 1024 * 2);     // 2 MB
  short* abc    = (short*)alloc((size_t)8 * 384 * 1024 * 2);     // 6 MB (hidden_a + gate_b + gate_c)
  short* feat   = (short*)alloc((size_t)8 * 384 * 1024 * 2);     // 6 MB
  short* emb_b  = (short*)alloc((size_t)32 * 128 * 1024 * 2);    // 8 MB
  short* emb_c  = (short*)alloc((size_t)128 * 128 * 1024 * 2);   // 32 MB
  short* regA   = (short*)alloc((size_t)128 * 64 * 1024 * 2);    // 16 MB: va_tok / xb / xc
  short* regB   = (short*)alloc((size_t)128 * 128 * 1024 * 2);   // 32 MB: hb / hc / h_r
  short* va_tok = regA;   // 4 MB
  short* xb     = regA;   // 8 MB (va_tok dead by then)
  short* xc     = regA;   // 16 MB (xb dead by then)
  short* hb     = regB;
  short* hc     = regB;
  short* h_r    = regB;

  WPack P;
  const WSeg segs[10] = {
    {(const float*)d_in[3],  OB_ABC,          32768},  // Wa1
    {(const float*)d_in[5],  OB_ABC + 32768,  32768},  // Wgb
    {(const float*)d_in[6],  OB_ABC + 65536,  32768},  // Wgc
    {(const float*)d_in[4],  OB_A2,           16384},
    {(const float*)d_in[7],  OB_B1,           16384},
    {(const float*)d_in[8],  OB_B2,           16384},
    {(const float*)d_in[9],  OB_C1,            8192},
    {(const float*)d_in[10], OB_C2,           16384},
    {(const float*)d_in[13], OB_R1,           98304},
    {(const float*)d_in[14], OB_R2,           65536}};
  for (int i = 0; i < 10; ++i) P.seg[i] = segs[i];

  dim3 blk(256);
  cvt_w<<<dim3(64, 10), blk, 0, stream>>>(P, wb);
  cvt_f2b<<<8192, blk, 0, stream>>>(vert_a, va_tok, 8 * 256 * 1024);
  // abc = [relu(Wa1@va); 1-sig(Wgb@va); 1-sig(Wgc@va)]   M=384 K=256 z=8
  mfma_gemm<3, short><<<dim3(8, 3, 8), blk, 0, stream>>>(wb + OB_ABC, va_tok, abc, 256, 256l * NTOK, 384l * NTOK);
  // emb_a = Wa2 @ hidden_a (abc rows 0-127)              M=128 K=128 z=8
  mfma_gemm<0, short><<<dim3(8, 1, 8), blk, 0, stream>>>(wb + OB_A2, abc, emb_a, 128, 384l * NTOK, 128l * NTOK);
  // b path
  tok_k<2, 128><<<16384, blk, 0, stream>>>(vert_b, xb, 64);
  mfma_gemm<1, short><<<dim3(8, 1, 32), blk, 0, stream>>>(wb + OB_B1, xb, hb, 128, 128l * NTOK, 128l * NTOK);
  mfma_gemm<0, short><<<dim3(8, 1, 32), blk, 0, stream>>>(wb + OB_B2, hb, emb_b, 128, 128l * NTOK, 128l * NTOK);
  // c path
  tok_k<4, 64><<<32768, blk, 0, stream>>>(vert_c, xc, 128);
  mfma_gemm<1, short><<<dim3(8, 1, 128), blk, 0, stream>>>(wb + OB_C1, xc, hc, 64, 64l * NTOK, 128l * NTOK);
  mfma_gemm<0, short><<<dim3(8, 1, 128), blk, 0, stream>>>(wb + OB_C2, hc, emb_c, 128, 128l * NTOK, 128l * NTOK);
  // attention
  score_k<<<dim3(4, 8),   blk, 0, stream>>>(emb_a, wab,       sa_b);
  score_k<<<dim3(4, 32),  blk, 0, stream>>>(emb_b, wab + 128, sb_b);
  score_k<<<dim3(4, 8),   blk, 0, stream>>>(emb_a, wac,       sa_c);
  score_k<<<dim3(4, 128), blk, 0, stream>>>(emb_c, wac + 128, sb_c);
  softmax_k<4>  <<<32, blk, 0, stream>>>(sa_b, sb_b, attn_b);
  softmax_k<16> <<<32, blk, 0, stream>>>(sa_c, sb_c, attn_c);
  feat_k<<<dim3(4, 384, 8), blk, 0, stream>>>(emb_b, emb_c, emb_a, abc, attn_b, attn_c, feat);
  // readout
  mfma_gemm<1, short><<<dim3(8, 2, 8), blk, 0, stream>>>(wb + OB_R1, feat, h_r, 384, 384l * NTOK, 256l * NTOK);
  mfma_gemm<0, float><<<dim3(8, 2, 8), blk, 0, stream>>>(wb + OB_R2, h_r, (float*)d_out, 256, 256l * NTOK, 256l * NTOK);
}

// Round 4
// 227.588 us; speedup vs baseline: 4.6930x; 1.1699x over previous
//
#include <hip/hip_runtime.h>
#include <hip/hip_bf16.h>

typedef __hip_bfloat16 bf16;
typedef __attribute__((ext_vector_type(8))) short v8s;   // 8 bf16 (MFMA A/B frag)
typedef __attribute__((ext_vector_type(4))) float v4f;   // MFMA C/D frag

__device__ __forceinline__ short f2s(float v){ bf16 h = __float2bfloat16(v); return *(short*)&h; }
__device__ __forceinline__ float s2f(short s){ bf16 h = *(bf16*)&s; return __bfloat162float(h); }
__device__ __forceinline__ unsigned pack2(float a, float b){
  return (unsigned)(unsigned short)f2s(a) | ((unsigned)(unsigned short)f2s(b) << 16);
}
__device__ __forceinline__ int SWZ(int row, int idx){ return idx ^ ((row & 7) << 3); }

#define NTOK 1024

// bf16 weight arena offsets (elements)
enum : int {
  OB_ABC = 0,                 // [384][256]: rows 0-127 Wa1, 128-255 Wgb, 256-383 Wgc
  OB_A2  = 98304,             // [128][128]
  OB_B1  = 114688,            // [128][128]
  OB_B2  = 131072,            // [128][128]
  OB_C1  = 147456,            // [128][64]
  OB_C2  = 155648,            // [128][128]
  OB_R1  = 172032,            // [256][384]
  OB_R2  = 270336,            // [256][256]
  OB_END = 335872
};

struct WSeg { const float* src; int off; int n; };
struct WPack { WSeg seg[10]; };

__global__ __launch_bounds__(256) void cvt_w(WPack P, short* __restrict__ wb) {
  WSeg s = P.seg[blockIdx.y];
  for (int i = blockIdx.x * 256 + threadIdx.x; i < s.n; i += gridDim.x * 256)
    wb[s.off + i] = f2s(s.src[i]);
}

// ================= a-path: [hidden;gate_b;gate_c] + emb_a + sa scores =================
// grid (16 n-tiles of 64, 8 z). 4 waves, each 32 M-rows x 64 N.
__global__ __launch_bounds__(256) void mlp_a_k(const short* __restrict__ wb,
                                               const float* __restrict__ va,
                                               const float* __restrict__ wab,
                                               const float* __restrict__ wac,
                                               short* __restrict__ emb_a,
                                               short* __restrict__ gate_b,
                                               short* __restrict__ gate_c,
                                               float* __restrict__ sa_b,
                                               float* __restrict__ sa_c) {
  __shared__ __align__(16) short Bs[64 * 256];   // va tile [n][k]
  __shared__ __align__(16) short As[128 * 64];   // weight chunk
  __shared__ __align__(16) short Ht[64 * 128];   // hidden^T [n][h]
  __shared__ float sbl[64], scl[64], wl[128], wcl[128];
  const int t = threadIdx.x;
  const int n0 = blockIdx.x * 64;
  const int z = blockIdx.y;
  const int l = t & 63, w = t >> 6;
  const int lr = l & 15, lk = (l >> 4) * 8, ro = (l >> 4) * 4;
  if (t < 128) { wl[t] = wab[t]; wcl[t] = wac[t]; }
  if (t < 64) { sbl[t] = 0.f; scl[t] = 0.f; }
  // stage va f32 -> Bs bf16 [64 n][256 k]
  {
    const int n = t & 63, kq = t >> 6;
    for (int it = 0; it < 8; ++it) {
      int k0 = (kq + 4 * it) * 8;
      v8s pk;
#pragma unroll
      for (int j = 0; j < 8; ++j) pk[j] = f2s(va[((long)z * 256 + k0 + j) * NTOK + n0 + n]);
      *(v8s*)&Bs[n * 256 + SWZ(n, k0)] = pk;
    }
  }
  const int ar = t >> 1, akh = (t & 1) * 32;
  v4f acc[2][4];
  // layer1: 3 M-passes (0: hidden->Ht, 1: gate_b, 2: gate_c)
  for (int p = 0; p < 3; ++p) {
#pragma unroll
    for (int mi = 0; mi < 2; ++mi)
#pragma unroll
      for (int ni = 0; ni < 4; ++ni) acc[mi][ni] = (v4f){0.f, 0.f, 0.f, 0.f};
    for (int k0 = 0; k0 < 256; k0 += 64) {
      __syncthreads();
#pragma unroll
      for (int c = 0; c < 4; ++c) {
        v8s pk = *(const v8s*)&wb[OB_ABC + (long)(p * 128 + ar) * 256 + k0 + akh + 8 * c];
        *(v8s*)&As[ar * 64 + SWZ(ar, akh + 8 * c)] = pk;
      }
      __syncthreads();
#pragma unroll
      for (int ks = 0; ks < 2; ++ks) {
        v8s af[2], bfv[4];
#pragma unroll
        for (int mi = 0; mi < 2; ++mi) { int m = w * 32 + mi * 16 + lr; af[mi] = *(const v8s*)&As[m * 64 + SWZ(m, ks * 32 + lk)]; }
#pragma unroll
        for (int ni = 0; ni < 4; ++ni) { int nn = ni * 16 + lr; bfv[ni] = *(const v8s*)&Bs[nn * 256 + SWZ(nn, k0 + ks * 32 + lk)]; }
#pragma unroll
        for (int mi = 0; mi < 2; ++mi)
#pragma unroll
          for (int ni = 0; ni < 4; ++ni)
            acc[mi][ni] = __builtin_amdgcn_mfma_f32_16x16x32_bf16(af[mi], bfv[ni], acc[mi][ni], 0, 0, 0);
      }
    }
    if (p == 0) {
#pragma unroll
      for (int mi = 0; mi < 2; ++mi)
#pragma unroll
        for (int ni = 0; ni < 4; ++ni) {
          int o = w * 32 + mi * 16 + ro, nn = ni * 16 + lr;
#pragma unroll
          for (int rp = 0; rp < 4; rp += 2)
            *(unsigned*)&Ht[nn * 128 + SWZ(nn, o + rp)] =
                pack2(fmaxf(acc[mi][ni][rp], 0.f), fmaxf(acc[mi][ni][rp + 1], 0.f));
        }
    } else {
      short* g = (p == 1) ? gate_b : gate_c;
#pragma unroll
      for (int mi = 0; mi < 2; ++mi)
#pragma unroll
        for (int ni = 0; ni < 4; ++ni)
#pragma unroll
          for (int r = 0; r < 4; ++r) {
            int o = w * 32 + mi * 16 + ro + r, nn = ni * 16 + lr;
            g[((long)z * 128 + o) * NTOK + n0 + nn] = f2s(1.f / (1.f + __expf(acc[mi][ni][r])));
          }
    }
  }
  __syncthreads();
  // layer2: emb_a = Wa2 @ hidden (K=128) + sa scores
#pragma unroll
  for (int mi = 0; mi < 2; ++mi)
#pragma unroll
    for (int ni = 0; ni < 4; ++ni) acc[mi][ni] = (v4f){0.f, 0.f, 0.f, 0.f};
  for (int k0 = 0; k0 < 128; k0 += 64) {
    __syncthreads();
#pragma unroll
    for (int c = 0; c < 4; ++c) {
      v8s pk = *(const v8s*)&wb[OB_A2 + (long)ar * 128 + k0 + akh + 8 * c];
      *(v8s*)&As[ar * 64 + SWZ(ar, akh + 8 * c)] = pk;
    }
    __syncthreads();
#pragma unroll
    for (int ks = 0; ks < 2; ++ks) {
      v8s af[2], bfv[4];
#pragma unroll
      for (int mi = 0; mi < 2; ++mi) { int m = w * 32 + mi * 16 + lr; af[mi] = *(const v8s*)&As[m * 64 + SWZ(m, ks * 32 + lk)]; }
#pragma unroll
      for (int ni = 0; ni < 4; ++ni) { int nn = ni * 16 + lr; bfv[ni] = *(const v8s*)&Ht[nn * 128 + SWZ(nn, k0 + ks * 32 + lk)]; }
#pragma unroll
      for (int mi = 0; mi < 2; ++mi)
#pragma unroll
        for (int ni = 0; ni < 4; ++ni)
          acc[mi][ni] = __builtin_amdgcn_mfma_f32_16x16x32_bf16(af[mi], bfv[ni], acc[mi][ni], 0, 0, 0);
    }
  }
#pragma unroll
  for (int ni = 0; ni < 4; ++ni) {
    int nn = ni * 16 + lr;
    float pb = 0.f, pc = 0.f;
#pragma unroll
    for (int mi = 0; mi < 2; ++mi)
#pragma unroll
      for (int r = 0; r < 4; ++r) {
        int o = w * 32 + mi * 16 + ro + r;
        float v = acc[mi][ni][r];
        emb_a[((long)z * 128 + o) * NTOK + n0 + nn] = f2s(v);
        pb = fmaf(wl[o], v, pb);
        pc = fmaf(wcl[o], v, pc);
      }
    atomicAdd(&sbl[nn], pb);
    atomicAdd(&scl[nn], pc);
  }
  __syncthreads();
  if (t < 64) {
    sa_b[(long)z * NTOK + n0 + t] = sbl[t];
    sa_c[(long)z * NTOK + n0 + t] = scl[t];
  }
}

// ================= fused 2-layer token MLP (unfold gather) + sb score =================
// grid (8 n-tiles of 128, Z). 4 waves in 2x2, 64x64 each.
template<int K1, int R, int HW>
__global__ __launch_bounds__(256) void mlp2_k(const short* __restrict__ w1,
                                              const short* __restrict__ w2,
                                              const float* __restrict__ V,
                                              const float* __restrict__ wvec,
                                              short* __restrict__ E,
                                              float* __restrict__ SB) {
  __shared__ __align__(16) short Bs[128 * 64];
  __shared__ __align__(16) short As[128 * 64];
  __shared__ __align__(16) short Ht[128 * 128];
  __shared__ float scl[128], wl[128];
  const int t = threadIdx.x;
  const int n0 = blockIdx.x * 128;
  const int z = blockIdx.y;
  const int P = R * R, b = z / P, p = z % P;
  const int dy = p / R, dx = p % R;
  const int l = t & 63, w = t >> 6;
  const int wr = w >> 1, wc = w & 1;
  const int lr = l & 15, lk = (l >> 4) * 8, ro = (l >> 4) * 4;
  if (t < 128) { wl[t] = wvec[t]; scl[t] = 0.f; }
  const int ar = t >> 1, akh = (t & 1) * 32;
  const int bn = t & 127, bkh = (t >> 7) * 32;
  v4f acc[4][4];
#pragma unroll
  for (int mi = 0; mi < 4; ++mi)
#pragma unroll
    for (int ni = 0; ni < 4; ++ni) acc[mi][ni] = (v4f){0.f, 0.f, 0.f, 0.f};
  // layer1 with fused unfold gather
  for (int k0 = 0; k0 < K1; k0 += 64) {
    __syncthreads();
#pragma unroll
    for (int c = 0; c < 4; ++c) {
      v8s pk = *(const v8s*)&w1[(long)ar * K1 + k0 + akh + 8 * c];
      *(v8s*)&As[ar * 64 + SWZ(ar, akh + 8 * c)] = pk;
    }
    {
      int n = n0 + bn, hn = n >> 5, wn = n & 31;
      const float* vp = V + ((long)(b * K1) * HW + hn * R + dy) * HW + wn * R + dx;
      const long kst = (long)HW * HW;
#pragma unroll
      for (int c = 0; c < 4; ++c) {
        v8s pk;
#pragma unroll
        for (int j = 0; j < 8; ++j) pk[j] = f2s(vp[(long)(k0 + bkh + 8 * c + j) * kst]);
        *(v8s*)&Bs[bn * 64 + SWZ(bn, bkh + 8 * c)] = pk;
      }
    }
    __syncthreads();
#pragma unroll
    for (int ks = 0; ks < 2; ++ks) {
      v8s af[4], bfv[4];
#pragma unroll
      for (int mi = 0; mi < 4; ++mi) { int m = wr * 64 + mi * 16 + lr; af[mi] = *(const v8s*)&As[m * 64 + SWZ(m, ks * 32 + lk)]; }
#pragma unroll
      for (int ni = 0; ni < 4; ++ni) { int nn = wc * 64 + ni * 16 + lr; bfv[ni] = *(const v8s*)&Bs[nn * 64 + SWZ(nn, ks * 32 + lk)]; }
#pragma unroll
      for (int mi = 0; mi < 4; ++mi)
#pragma unroll
        for (int ni = 0; ni < 4; ++ni)
          acc[mi][ni] = __builtin_amdgcn_mfma_f32_16x16x32_bf16(af[mi], bfv[ni], acc[mi][ni], 0, 0, 0);
    }
  }
  __syncthreads();
  // hidden -> Ht (relu, transposed, swizzled)
#pragma unroll
  for (int mi = 0; mi < 4; ++mi)
#pragma unroll
    for (int ni = 0; ni < 4; ++ni) {
      int o = wr * 64 + mi * 16 + ro, nn = wc * 64 + ni * 16 + lr;
#pragma unroll
      for (int rp = 0; rp < 4; rp += 2)
        *(unsigned*)&Ht[nn * 128 + SWZ(nn, o + rp)] =
            pack2(fmaxf(acc[mi][ni][rp], 0.f), fmaxf(acc[mi][ni][rp + 1], 0.f));
    }
  // layer2 (K=128)
#pragma unroll
  for (int mi = 0; mi < 4; ++mi)
#pragma unroll
    for (int ni = 0; ni < 4; ++ni) acc[mi][ni] = (v4f){0.f, 0.f, 0.f, 0.f};
  for (int k0 = 0; k0 < 128; k0 += 64) {
    __syncthreads();
#pragma unroll
    for (int c = 0; c < 4; ++c) {
      v8s pk = *(const v8s*)&w2[(long)ar * 128 + k0 + akh + 8 * c];
      *(v8s*)&As[ar * 64 + SWZ(ar, akh + 8 * c)] = pk;
    }
    __syncthreads();
#pragma unroll
    for (int ks = 0; ks < 2; ++ks) {
      v8s af[4], bfv[4];
#pragma unroll
      for (int mi = 0; mi < 4; ++mi) { int m = wr * 64 + mi * 16 + lr; af[mi] = *(const v8s*)&As[m * 64 + SWZ(m, ks * 32 + lk)]; }
#pragma unroll
      for (int ni = 0; ni < 4; ++ni) { int nn = wc * 64 + ni * 16 + lr; bfv[ni] = *(const v8s*)&Ht[nn * 128 + SWZ(nn, k0 + ks * 32 + lk)]; }
#pragma unroll
      for (int mi = 0; mi < 4; ++mi)
#pragma unroll
        for (int ni = 0; ni < 4; ++ni)
          acc[mi][ni] = __builtin_amdgcn_mfma_f32_16x16x32_bf16(af[mi], bfv[ni], acc[mi][ni], 0, 0, 0);
    }
  }
  // epilogue: emb + score partials
#pragma unroll
  for (int ni = 0; ni < 4; ++ni) {
    int nn = wc * 64 + ni * 16 + lr;
    float pb = 0.f;
#pragma unroll
    for (int mi = 0; mi < 4; ++mi)
#pragma unroll
      for (int r = 0; r < 4; ++r) {
        int o = wr * 64 + mi * 16 + ro + r;
        float v = acc[mi][ni][r];
        E[((long)z * 128 + o) * NTOK + n0 + nn] = f2s(v);
        pb = fmaf(wl[o], v, pb);
      }
    atomicAdd(&scl[nn], pb);
  }
  __syncthreads();
  if (t < 128) SB[(long)z * NTOK + n0 + t] = scl[t];
}

// ================= feat = sigmoid([agg_b*gate_b ; agg_c*gate_c ; emb_a]) =================
// softmax inline. grid (32 n-tiles of 32, 8 b); thread: n = t&31, c-range = (t>>5)*48.
__global__ __launch_bounds__(256) void feat2_k(const short* __restrict__ emb_b,
                                               const short* __restrict__ emb_c,
                                               const short* __restrict__ emb_a,
                                               const short* __restrict__ gate_b,
                                               const short* __restrict__ gate_c,
                                               const float* __restrict__ sa_b,
                                               const float* __restrict__ sb_b,
                                               const float* __restrict__ sa_c,
                                               const float* __restrict__ sb_c,
                                               short* __restrict__ feat) {
  const int t = threadIdx.x;
  const int n = blockIdx.x * 32 + (t & 31);
  const int b = blockIdx.y;
  float ab[4], ac[16];
  {
    float sa = sa_b[b * NTOK + n], m = 0.f, s[4], den = 0.f;
#pragma unroll
    for (int p = 0; p < 4; ++p) { s[p] = fmaxf(sa + sb_b[((long)b * 4 + p) * NTOK + n], 0.f); m = fmaxf(m, s[p]); }
#pragma unroll
    for (int p = 0; p < 4; ++p) { s[p] = __expf(s[p] - m); den += s[p]; }
    float r = 1.f / den;
#pragma unroll
    for (int p = 0; p < 4; ++p) ab[p] = s[p] * r;
  }
  {
    float sa = sa_c[b * NTOK + n], m = 0.f, s[16], den = 0.f;
#pragma unroll
    for (int p = 0; p < 16; ++p) { s[p] = fmaxf(sa + sb_c[((long)b * 16 + p) * NTOK + n], 0.f); m = fmaxf(m, s[p]); }
#pragma unroll
    for (int p = 0; p < 16; ++p) { s[p] = __expf(s[p] - m); den += s[p]; }
    float r = 1.f / den;
#pragma unroll
    for (int p = 0; p < 16; ++p) ac[p] = s[p] * r;
  }
  const int c0 = (t >> 5) * 48;
  for (int c = c0; c < c0 + 48; ++c) {
    float v;
    if (c < 128) {
      v = 0.f;
#pragma unroll
      for (int p = 0; p < 4; ++p)
        v = fmaf(s2f(emb_b[(((long)b * 4 + p) * 128 + c) * NTOK + n]), ab[p], v);
      v *= s2f(gate_b[((long)b * 128 + c) * NTOK + n]);
    } else if (c < 256) {
      int cc = c - 128;
      v = 0.f;
#pragma unroll
      for (int p = 0; p < 16; ++p)
        v = fmaf(s2f(emb_c[(((long)b * 16 + p) * 128 + cc) * NTOK + n]), ac[p], v);
      v *= s2f(gate_c[((long)b * 128 + cc) * NTOK + n]);
    } else {
      v = s2f(emb_a[((long)b * 128 + (c - 256)) * NTOK + n]);
    }
    v = 1.f / (1.f + __expf(-v));
    feat[((long)b * 384 + c) * NTOK + n] = f2s(v);
  }
}

// ================= fused readout: out = Wr2 @ relu(Wr1 @ feat) =================
// grid (16 n-tiles of 64, 8 z). 4 waves stacked in M (64 rows each).
__global__ __launch_bounds__(256) void r12_k(const short* __restrict__ wb,
                                             const short* __restrict__ feat,
                                             float* __restrict__ out) {
  __shared__ __align__(16) short Bs[64 * 64];
  __shared__ __align__(16) short As[256 * 64];
  __shared__ __align__(16) short Ht[64 * 256];
  const int t = threadIdx.x;
  const int n0 = blockIdx.x * 64;
  const int z = blockIdx.y;
  const int l = t & 63, w = t >> 6;
  const int lr = l & 15, lk = (l >> 4) * 8, ro = (l >> 4) * 4;
  const int bn = t & 63, kq = t >> 6;
  v4f acc[4][4];
#pragma unroll
  for (int mi = 0; mi < 4; ++mi)
#pragma unroll
    for (int ni = 0; ni < 4; ++ni) acc[mi][ni] = (v4f){0.f, 0.f, 0.f, 0.f};
  for (int k0 = 0; k0 < 384; k0 += 64) {
    __syncthreads();
#pragma unroll
    for (int c = 0; c < 8; ++c) {
      v8s pk = *(const v8s*)&wb[OB_R1 + (long)t * 384 + k0 + 8 * c];
      *(v8s*)&As[t * 64 + SWZ(t, 8 * c)] = pk;
    }
#pragma unroll
    for (int c = 0; c < 2; ++c) {
      v8s pk;
#pragma unroll
      for (int j = 0; j < 8; ++j) pk[j] = feat[((long)z * 384 + k0 + kq * 16 + 8 * c + j) * NTOK + n0 + bn];
      *(v8s*)&Bs[bn * 64 + SWZ(bn, kq * 16 + 8 * c)] = pk;
    }
    __syncthreads();
#pragma unroll
    for (int ks = 0; ks < 2; ++ks) {
      v8s af[4], bfv[4];
#pragma unroll
      for (int mi = 0; mi < 4; ++mi) { int m = w * 64 + mi * 16 + lr; af[mi] = *(const v8s*)&As[m * 64 + SWZ(m, ks * 32 + lk)]; }
#pragma unroll
      for (int ni = 0; ni < 4; ++ni) { int nn = ni * 16 + lr; bfv[ni] = *(const v8s*)&Bs[nn * 64 + SWZ(nn, ks * 32 + lk)]; }
#pragma unroll
      for (int mi = 0; mi < 4; ++mi)
#pragma unroll
        for (int ni = 0; ni < 4; ++ni)
          acc[mi][ni] = __builtin_amdgcn_mfma_f32_16x16x32_bf16(af[mi], bfv[ni], acc[mi][ni], 0, 0, 0);
    }
  }
  __syncthreads();
#pragma unroll
  for (int mi = 0; mi < 4; ++mi)
#pragma unroll
    for (int ni = 0; ni < 4; ++ni) {
      int o = w * 64 + mi * 16 + ro, nn = ni * 16 + lr;
#pragma unroll
      for (int rp = 0; rp < 4; rp += 2)
        *(unsigned*)&Ht[nn * 256 + SWZ(nn, o + rp)] =
            pack2(fmaxf(acc[mi][ni][rp], 0.f), fmaxf(acc[mi][ni][rp + 1], 0.f));
    }
#pragma unroll
  for (int mi = 0; mi < 4; ++mi)
#pragma unroll
    for (int ni = 0; ni < 4; ++ni) acc[mi][ni] = (v4f){0.f, 0.f, 0.f, 0.f};
  for (int k0 = 0; k0 < 256; k0 += 64) {
    __syncthreads();
#pragma unroll
    for (int c = 0; c < 8; ++c) {
      v8s pk = *(const v8s*)&wb[OB_R2 + (long)t * 256 + k0 + 8 * c];
      *(v8s*)&As[t * 64 + SWZ(t, 8 * c)] = pk;
    }
    __syncthreads();
#pragma unroll
    for (int ks = 0; ks < 2; ++ks) {
      v8s af[4], bfv[4];
#pragma unroll
      for (int mi = 0; mi < 4; ++mi) { int m = w * 64 + mi * 16 + lr; af[mi] = *(const v8s*)&As[m * 64 + SWZ(m, ks * 32 + lk)]; }
#pragma unroll
      for (int ni = 0; ni < 4; ++ni) { int nn = ni * 16 + lr; bfv[ni] = *(const v8s*)&Ht[nn * 256 + SWZ(nn, k0 + ks * 32 + lk)]; }
#pragma unroll
      for (int mi = 0; mi < 4; ++mi)
#pragma unroll
        for (int ni = 0; ni < 4; ++ni)
          acc[mi][ni] = __builtin_amdgcn_mfma_f32_16x16x32_bf16(af[mi], bfv[ni], acc[mi][ni], 0, 0, 0);
    }
  }
#pragma unroll
  for (int mi = 0; mi < 4; ++mi)
#pragma unroll
    for (int ni = 0; ni < 4; ++ni)
#pragma unroll
      for (int r = 0; r < 4; ++r) {
        int o = w * 64 + mi * 16 + ro + r, nn = ni * 16 + lr;
        out[((long)z * 256 + o) * NTOK + n0 + nn] = acc[mi][ni][r];
      }
}

extern "C" void kernel_launch(void* const* d_in, const int* in_sizes, int n_in,
                              void* d_out, int out_size, void* d_ws, size_t ws_size,
                              hipStream_t stream) {
  const float* vert_a = (const float*)d_in[0];
  const float* vert_b = (const float*)d_in[1];
  const float* vert_c = (const float*)d_in[2];
  const float* wab = (const float*)d_in[11];
  const float* wac = (const float*)d_in[12];

  char* wsb = (char*)d_ws;
  size_t off = 0;
  auto alloc = [&](size_t bytes) { char* p = wsb + off; off += (bytes + 255) & ~(size_t)255; return p; };
  short* wb     = (short*)alloc((size_t)OB_END * 2);
  float* sa_b   = (float*)alloc(8192 * 4);
  float* sa_c   = (float*)alloc(8192 * 4);
  float* sb_b   = (float*)alloc(32768 * 4);
  float* sb_c   = (float*)alloc(131072 * 4);
  short* emb_a  = (short*)alloc((size_t)8 * 128 * 1024 * 2);
  short* gate_b = (short*)alloc((size_t)8 * 128 * 1024 * 2);
  short* gate_c = (short*)alloc((size_t)8 * 128 * 1024 * 2);
  short* emb_b  = (short*)alloc((size_t)32 * 128 * 1024 * 2);
  short* emb_c  = (short*)alloc((size_t)128 * 128 * 1024 * 2);
  short* feat   = (short*)alloc((size_t)8 * 384 * 1024 * 2);

  WPack P;
  const WSeg segs[10] = {
    {(const float*)d_in[3],  OB_ABC,          32768},
    {(const float*)d_in[5],  OB_ABC + 32768,  32768},
    {(const float*)d_in[6],  OB_ABC + 65536,  32768},
    {(const float*)d_in[4],  OB_A2,           16384},
    {(const float*)d_in[7],  OB_B1,           16384},
    {(const float*)d_in[8],  OB_B2,           16384},
    {(const float*)d_in[9],  OB_C1,            8192},
    {(const float*)d_in[10], OB_C2,           16384},
    {(const float*)d_in[13], OB_R1,           98304},
    {(const float*)d_in[14], OB_R2,           65536}};
  for (int i = 0; i < 10; ++i) P.seg[i] = segs[i];

  dim3 blk(256);
  cvt_w<<<dim3(64, 10), blk, 0, stream>>>(P, wb);
  mlp_a_k<<<dim3(16, 8), blk, 0, stream>>>(wb, vert_a, wab, wac, emb_a, gate_b, gate_c, sa_b, sa_c);
  mlp2_k<128, 2, 64> <<<dim3(8, 32),  blk, 0, stream>>>(wb + OB_B1, wb + OB_B2, vert_b, wab + 128, emb_b, sb_b);
  mlp2_k<64, 4, 128> <<<dim3(8, 128), blk, 0, stream>>>(wb + OB_C1, wb + OB_C2, vert_c, wac + 128, emb_c, sb_c);
  feat2_k<<<dim3(32, 8), blk, 0, stream>>>(emb_b, emb_c, emb_a, gate_b, gate_c,
                                           sa_b, sb_b, sa_c, sb_c, feat);
  r12_k<<<dim3(16, 8), blk, 0, stream>>>(wb, feat, (float*)d_out);
}

// Round 5
// 226.080 us; speedup vs baseline: 4.7243x; 1.0067x over previous
//
#include <hip/hip_runtime.h>
#include <hip/hip_bf16.h>

typedef __hip_bfloat16 bf16;
typedef __attribute__((ext_vector_type(8))) short v8s;   // 8 bf16 (MFMA A/B frag)
typedef __attribute__((ext_vector_type(4))) float v4f;   // MFMA C/D frag

__device__ __forceinline__ short f2s(float v){ bf16 h = __float2bfloat16(v); return *(short*)&h; }
__device__ __forceinline__ float s2f(short s){ bf16 h = *(bf16*)&s; return __bfloat162float(h); }
__device__ __forceinline__ unsigned pack2(float a, float b){
  return (unsigned)(unsigned short)f2s(a) | ((unsigned)(unsigned short)f2s(b) << 16);
}
__device__ __forceinline__ int SWZ(int row, int idx){ return idx ^ ((row & 7) << 3); }

#define NTOK 1024

enum : int {
  OB_ABC = 0,                 // [384][256]: rows 0-127 Wa1, 128-255 Wgb, 256-383 Wgc
  OB_A2  = 98304,             // [128][128]
  OB_B1  = 114688,            // [128][128]
  OB_B2  = 131072,            // [128][128]
  OB_C1  = 147456,            // [128][64]
  OB_C2  = 155648,            // [128][128]
  OB_R1  = 172032,            // [256][384]
  OB_R2  = 270336,            // [256][256]
  OB_END = 335872
};

struct WSeg { const float* src; int off; int n; };
struct WPack { WSeg seg[10]; };

// ======== phase0: tokenize (coalesced transpose via LDS) + weight convert ========
// tok: per (b,k) block reads the full HW x HW f32 plane contiguously, emits
// T[(b*R*R+p)][k][n] bf16 with p=(y%R)*R+(x%R), n=(y/R)*32+(x/R).
template<int R, int HW, int K>
__device__ __forceinline__ void tok_dev(const float* __restrict__ V, short* __restrict__ T,
                                        int b, int k, char* smem) {
  short* L = (short*)smem;  // [R*R][1024]
  const int t = threadIdx.x;
  const float4* src = (const float4*)(V + ((long)b * K + k) * HW * HW);
  constexpr int NF4 = HW * HW / 4;
  constexpr int P2 = R * R;
  for (int idx = t; idx < NF4; idx += 256) {
    int y = idx / (HW / 4);
    int x4 = (idx % (HW / 4)) * 4;
    float4 v = src[idx];
    float vv[4] = {v.x, v.y, v.z, v.w};
    int pb = (y % R) * R, ny = (y / R) * 32;
#pragma unroll
    for (int j = 0; j < 4; ++j) {
      int x = x4 + j;
      L[(pb + (x % R)) * 1024 + ny + x / R] = f2s(vv[j]);
    }
  }
  __syncthreads();
  for (int idx = t; idx < P2 * 128; idx += 256) {
    int p = idx >> 7, c8 = (idx & 127) * 8;
    *(v8s*)&T[((long)(b * P2 + p) * K + k) * 1024 + c8] = *(const v8s*)&L[p * 1024 + c8];
  }
}

__global__ __launch_bounds__(256) void phase0_k(WPack P, short* __restrict__ wb,
                                                const float* __restrict__ vb,
                                                const float* __restrict__ vc,
                                                short* __restrict__ Tb,
                                                short* __restrict__ Tc) {
  __shared__ __align__(16) char smem[32768];
  int bid = blockIdx.x;
  if (bid < 512) {                         // vert_c: 8 b x 64 k
    tok_dev<4, 128, 64>(vc, Tc, bid >> 6, bid & 63, smem);
  } else if (bid < 1536) {                 // vert_b: 8 b x 128 k
    int i = bid - 512;
    tok_dev<2, 64, 128>(vb, Tb, i >> 7, i & 127, smem);
  } else {                                 // weight convert: 640 blocks
    int i = bid - 1536;
    WSeg s = P.seg[i / 64];
    for (int j = (i & 63) * 256 + threadIdx.x; j < s.n; j += 16384)
      wb[s.off + j] = f2s(s.src[j]);
  }
}

// ======== phase1 device: a-path ========
__device__ __forceinline__ void mlp_a_dev(char* smem, const short* __restrict__ wb,
                                          const float* __restrict__ va,
                                          const float* __restrict__ wab,
                                          const float* __restrict__ wac,
                                          short* __restrict__ emb_a,
                                          short* __restrict__ gate_b,
                                          short* __restrict__ gate_c,
                                          float* __restrict__ sa_b,
                                          float* __restrict__ sa_c,
                                          int nx, int z) {
  short* Bs = (short*)smem;              // [64 n][256 k]
  short* As = (short*)(smem + 32768);    // [128 m][64 k]
  short* Ht = (short*)(smem + 49152);    // [64 n][128 h]
  float* sbl = (float*)(smem + 65536);
  float* scl = (float*)(smem + 65792);
  float* wl  = (float*)(smem + 66048);
  float* wcl = (float*)(smem + 66560);
  const int t = threadIdx.x;
  const int n0 = nx * 64;
  const int l = t & 63, w = t >> 6;
  const int lr = l & 15, lk = (l >> 4) * 8, ro = (l >> 4) * 4;
  if (t < 128) { wl[t] = wab[t]; wcl[t] = wac[t]; }
  if (t < 64) { sbl[t] = 0.f; scl[t] = 0.f; }
  {
    const int n = t & 63, kq = t >> 6;
    for (int it = 0; it < 8; ++it) {
      int k0 = (kq + 4 * it) * 8;
      v8s pk;
#pragma unroll
      for (int j = 0; j < 8; ++j) pk[j] = f2s(va[((long)z * 256 + k0 + j) * NTOK + n0 + n]);
      *(v8s*)&Bs[n * 256 + SWZ(n, k0)] = pk;
    }
  }
  const int ar = t >> 1, akh = (t & 1) * 32;
  v4f acc[2][4];
  for (int p = 0; p < 3; ++p) {
#pragma unroll
    for (int mi = 0; mi < 2; ++mi)
#pragma unroll
      for (int ni = 0; ni < 4; ++ni) acc[mi][ni] = (v4f){0.f, 0.f, 0.f, 0.f};
    for (int k0 = 0; k0 < 256; k0 += 64) {
      __syncthreads();
#pragma unroll
      for (int c = 0; c < 4; ++c) {
        v8s pk = *(const v8s*)&wb[OB_ABC + (long)(p * 128 + ar) * 256 + k0 + akh + 8 * c];
        *(v8s*)&As[ar * 64 + SWZ(ar, akh + 8 * c)] = pk;
      }
      __syncthreads();
#pragma unroll
      for (int ks = 0; ks < 2; ++ks) {
        v8s af[2], bfv[4];
#pragma unroll
        for (int mi = 0; mi < 2; ++mi) { int m = w * 32 + mi * 16 + lr; af[mi] = *(const v8s*)&As[m * 64 + SWZ(m, ks * 32 + lk)]; }
#pragma unroll
        for (int ni = 0; ni < 4; ++ni) { int nn = ni * 16 + lr; bfv[ni] = *(const v8s*)&Bs[nn * 256 + SWZ(nn, k0 + ks * 32 + lk)]; }
#pragma unroll
        for (int mi = 0; mi < 2; ++mi)
#pragma unroll
          for (int ni = 0; ni < 4; ++ni)
            acc[mi][ni] = __builtin_amdgcn_mfma_f32_16x16x32_bf16(af[mi], bfv[ni], acc[mi][ni], 0, 0, 0);
      }
    }
    if (p == 0) {
#pragma unroll
      for (int mi = 0; mi < 2; ++mi)
#pragma unroll
        for (int ni = 0; ni < 4; ++ni) {
          int o = w * 32 + mi * 16 + ro, nn = ni * 16 + lr;
#pragma unroll
          for (int rp = 0; rp < 4; rp += 2)
            *(unsigned*)&Ht[nn * 128 + SWZ(nn, o + rp)] =
                pack2(fmaxf(acc[mi][ni][rp], 0.f), fmaxf(acc[mi][ni][rp + 1], 0.f));
        }
    } else {
      short* g = (p == 1) ? gate_b : gate_c;
#pragma unroll
      for (int mi = 0; mi < 2; ++mi)
#pragma unroll
        for (int ni = 0; ni < 4; ++ni)
#pragma unroll
          for (int r = 0; r < 4; ++r) {
            int o = w * 32 + mi * 16 + ro + r, nn = ni * 16 + lr;
            g[((long)z * 128 + o) * NTOK + n0 + nn] = f2s(1.f / (1.f + __expf(acc[mi][ni][r])));
          }
    }
  }
  __syncthreads();
#pragma unroll
  for (int mi = 0; mi < 2; ++mi)
#pragma unroll
    for (int ni = 0; ni < 4; ++ni) acc[mi][ni] = (v4f){0.f, 0.f, 0.f, 0.f};
  for (int k0 = 0; k0 < 128; k0 += 64) {
    __syncthreads();
#pragma unroll
    for (int c = 0; c < 4; ++c) {
      v8s pk = *(const v8s*)&wb[OB_A2 + (long)ar * 128 + k0 + akh + 8 * c];
      *(v8s*)&As[ar * 64 + SWZ(ar, akh + 8 * c)] = pk;
    }
    __syncthreads();
#pragma unroll
    for (int ks = 0; ks < 2; ++ks) {
      v8s af[2], bfv[4];
#pragma unroll
      for (int mi = 0; mi < 2; ++mi) { int m = w * 32 + mi * 16 + lr; af[mi] = *(const v8s*)&As[m * 64 + SWZ(m, ks * 32 + lk)]; }
#pragma unroll
      for (int ni = 0; ni < 4; ++ni) { int nn = ni * 16 + lr; bfv[ni] = *(const v8s*)&Ht[nn * 128 + SWZ(nn, k0 + ks * 32 + lk)]; }
#pragma unroll
      for (int mi = 0; mi < 2; ++mi)
#pragma unroll
        for (int ni = 0; ni < 4; ++ni)
          acc[mi][ni] = __builtin_amdgcn_mfma_f32_16x16x32_bf16(af[mi], bfv[ni], acc[mi][ni], 0, 0, 0);
    }
  }
#pragma unroll
  for (int ni = 0; ni < 4; ++ni) {
    int nn = ni * 16 + lr;
    float pb = 0.f, pc = 0.f;
#pragma unroll
    for (int mi = 0; mi < 2; ++mi)
#pragma unroll
      for (int r = 0; r < 4; ++r) {
        int o = w * 32 + mi * 16 + ro + r;
        float v = acc[mi][ni][r];
        emb_a[((long)z * 128 + o) * NTOK + n0 + nn] = f2s(v);
        pb = fmaf(wl[o], v, pb);
        pc = fmaf(wcl[o], v, pc);
      }
    atomicAdd(&sbl[nn], pb);
    atomicAdd(&scl[nn], pc);
  }
  __syncthreads();
  if (t < 64) {
    sa_b[(long)z * NTOK + n0 + t] = sbl[t];
    sa_c[(long)z * NTOK + n0 + t] = scl[t];
  }
}

// ======== phase1 device: token MLP (2 layers, reads tokenized bf16) ========
template<int K1>
__device__ __forceinline__ void mlp2_dev(char* smem, const short* __restrict__ w1,
                                         const short* __restrict__ w2,
                                         const short* __restrict__ T,   // [z][K1][1024]
                                         const float* __restrict__ wvec,
                                         short* __restrict__ E,
                                         float* __restrict__ SB,
                                         int nx, int z) {
  short* Bs = (short*)smem;              // [128 n][64 k]
  short* As = (short*)(smem + 16384);    // [128 m][64 k]
  short* Ht = (short*)(smem + 32768);    // [128 n][128 h]
  float* scl = (float*)(smem + 65536);
  float* wl  = (float*)(smem + 66048);
  const int t = threadIdx.x;
  const int n0 = nx * 128;
  const int l = t & 63, w = t >> 6;
  const int wr = w >> 1, wc = w & 1;
  const int lr = l & 15, lk = (l >> 4) * 8, ro = (l >> 4) * 4;
  if (t < 128) { wl[t] = wvec[t]; scl[t] = 0.f; }
  const int ar = t >> 1, akh = (t & 1) * 32;
  const int bn = t & 127, bkh = (t >> 7) * 32;
  const short* xz = T + (long)z * K1 * NTOK;
  v4f acc[4][4];
#pragma unroll
  for (int mi = 0; mi < 4; ++mi)
#pragma unroll
    for (int ni = 0; ni < 4; ++ni) acc[mi][ni] = (v4f){0.f, 0.f, 0.f, 0.f};
  for (int k0 = 0; k0 < K1; k0 += 64) {
    __syncthreads();
#pragma unroll
    for (int c = 0; c < 4; ++c) {
      v8s pk = *(const v8s*)&w1[(long)ar * K1 + k0 + akh + 8 * c];
      *(v8s*)&As[ar * 64 + SWZ(ar, akh + 8 * c)] = pk;
    }
    {
      const short* xcol = xz + (long)(k0 + bkh) * NTOK + n0 + bn;
#pragma unroll
      for (int c = 0; c < 4; ++c) {
        v8s pk;
#pragma unroll
        for (int j = 0; j < 8; ++j) pk[j] = xcol[(long)(8 * c + j) * NTOK];
        *(v8s*)&Bs[bn * 64 + SWZ(bn, bkh + 8 * c)] = pk;
      }
    }
    __syncthreads();
#pragma unroll
    for (int ks = 0; ks < 2; ++ks) {
      v8s af[4], bfv[4];
#pragma unroll
      for (int mi = 0; mi < 4; ++mi) { int m = wr * 64 + mi * 16 + lr; af[mi] = *(const v8s*)&As[m * 64 + SWZ(m, ks * 32 + lk)]; }
#pragma unroll
      for (int ni = 0; ni < 4; ++ni) { int nn = wc * 64 + ni * 16 + lr; bfv[ni] = *(const v8s*)&Bs[nn * 64 + SWZ(nn, ks * 32 + lk)]; }
#pragma unroll
      for (int mi = 0; mi < 4; ++mi)
#pragma unroll
        for (int ni = 0; ni < 4; ++ni)
          acc[mi][ni] = __builtin_amdgcn_mfma_f32_16x16x32_bf16(af[mi], bfv[ni], acc[mi][ni], 0, 0, 0);
    }
  }
  __syncthreads();
#pragma unroll
  for (int mi = 0; mi < 4; ++mi)
#pragma unroll
    for (int ni = 0; ni < 4; ++ni) {
      int o = wr * 64 + mi * 16 + ro, nn = wc * 64 + ni * 16 + lr;
#pragma unroll
      for (int rp = 0; rp < 4; rp += 2)
        *(unsigned*)&Ht[nn * 128 + SWZ(nn, o + rp)] =
            pack2(fmaxf(acc[mi][ni][rp], 0.f), fmaxf(acc[mi][ni][rp + 1], 0.f));
    }
#pragma unroll
  for (int mi = 0; mi < 4; ++mi)
#pragma unroll
    for (int ni = 0; ni < 4; ++ni) acc[mi][ni] = (v4f){0.f, 0.f, 0.f, 0.f};
  for (int k0 = 0; k0 < 128; k0 += 64) {
    __syncthreads();
#pragma unroll
    for (int c = 0; c < 4; ++c) {
      v8s pk = *(const v8s*)&w2[(long)ar * 128 + k0 + akh + 8 * c];
      *(v8s*)&As[ar * 64 + SWZ(ar, akh + 8 * c)] = pk;
    }
    __syncthreads();
#pragma unroll
    for (int ks = 0; ks < 2; ++ks) {
      v8s af[4], bfv[4];
#pragma unroll
      for (int mi = 0; mi < 4; ++mi) { int m = wr * 64 + mi * 16 + lr; af[mi] = *(const v8s*)&As[m * 64 + SWZ(m, ks * 32 + lk)]; }
#pragma unroll
      for (int ni = 0; ni < 4; ++ni) { int nn = wc * 64 + ni * 16 + lr; bfv[ni] = *(const v8s*)&Ht[nn * 128 + SWZ(nn, k0 + ks * 32 + lk)]; }
#pragma unroll
      for (int mi = 0; mi < 4; ++mi)
#pragma unroll
        for (int ni = 0; ni < 4; ++ni)
          acc[mi][ni] = __builtin_amdgcn_mfma_f32_16x16x32_bf16(af[mi], bfv[ni], acc[mi][ni], 0, 0, 0);
    }
  }
#pragma unroll
  for (int ni = 0; ni < 4; ++ni) {
    int nn = wc * 64 + ni * 16 + lr;
    float pb = 0.f;
#pragma unroll
    for (int mi = 0; mi < 4; ++mi)
#pragma unroll
      for (int r = 0; r < 4; ++r) {
        int o = wr * 64 + mi * 16 + ro + r;
        float v = acc[mi][ni][r];
        E[((long)z * 128 + o) * NTOK + n0 + nn] = f2s(v);
        pb = fmaf(wl[o], v, pb);
      }
    atomicAdd(&scl[nn], pb);
  }
  __syncthreads();
  if (t < 128) SB[(long)z * NTOK + n0 + t] = scl[t];
}

// ======== phase1: mlp2_c [0,1024) + mlp2_b [1024,1280) + mlp_a [1280,1408) ========
__global__ __launch_bounds__(256) void phase1_k(const short* __restrict__ wb,
                                                const float* __restrict__ va,
                                                const short* __restrict__ Tb,
                                                const short* __restrict__ Tc,
                                                const float* __restrict__ wab,
                                                const float* __restrict__ wac,
                                                short* emb_a, short* gate_b, short* gate_c,
                                                short* emb_b, short* emb_c,
                                                float* sa_b, float* sa_c,
                                                float* sb_b, float* sb_c) {
  __shared__ __align__(16) char smem[67584];
  int bid = blockIdx.x;
  if (bid < 1024) {
    mlp2_dev<64>(smem, wb + OB_C1, wb + OB_C2, Tc, wac + 128, emb_c, sb_c, bid & 7, bid >> 3);
  } else if (bid < 1280) {
    int i = bid - 1024;
    mlp2_dev<128>(smem, wb + OB_B1, wb + OB_B2, Tb, wab + 128, emb_b, sb_b, i & 7, i >> 3);
  } else {
    int i = bid - 1280;
    mlp_a_dev(smem, wb, va, wab, wac, emb_a, gate_b, gate_c, sa_b, sa_c, i & 15, i >> 4);
  }
}

// ======== feat = sigmoid([agg_b*gate_b ; agg_c*gate_c ; emb_a]) ========
// grid (16 n-tiles of 64, 8 b); thread: n = t&63, c-range = (t>>6)*96.
__global__ __launch_bounds__(256) void feat2_k(const short* __restrict__ emb_b,
                                               const short* __restrict__ emb_c,
                                               const short* __restrict__ emb_a,
                                               const short* __restrict__ gate_b,
                                               const short* __restrict__ gate_c,
                                               const float* __restrict__ sa_b,
                                               const float* __restrict__ sb_b,
                                               const float* __restrict__ sa_c,
                                               const float* __restrict__ sb_c,
                                               short* __restrict__ feat) {
  const int t = threadIdx.x;
  const int n = blockIdx.x * 64 + (t & 63);
  const int b = blockIdx.y;
  float ab[4], ac[16];
  {
    float sa = sa_b[b * NTOK + n], m = 0.f, s[4], den = 0.f;
#pragma unroll
    for (int p = 0; p < 4; ++p) { s[p] = fmaxf(sa + sb_b[((long)b * 4 + p) * NTOK + n], 0.f); m = fmaxf(m, s[p]); }
#pragma unroll
    for (int p = 0; p < 4; ++p) { s[p] = __expf(s[p] - m); den += s[p]; }
    float r = 1.f / den;
#pragma unroll
    for (int p = 0; p < 4; ++p) ab[p] = s[p] * r;
  }
  {
    float sa = sa_c[b * NTOK + n], m = 0.f, s[16], den = 0.f;
#pragma unroll
    for (int p = 0; p < 16; ++p) { s[p] = fmaxf(sa + sb_c[((long)b * 16 + p) * NTOK + n], 0.f); m = fmaxf(m, s[p]); }
#pragma unroll
    for (int p = 0; p < 16; ++p) { s[p] = __expf(s[p] - m); den += s[p]; }
    float r = 1.f / den;
#pragma unroll
    for (int p = 0; p < 16; ++p) ac[p] = s[p] * r;
  }
  const int c0 = (t >> 6) * 96;
  for (int c = c0; c < c0 + 96; ++c) {
    float v;
    if (c < 128) {
      v = 0.f;
#pragma unroll
      for (int p = 0; p < 4; ++p)
        v = fmaf(s2f(emb_b[(((long)b * 4 + p) * 128 + c) * NTOK + n]), ab[p], v);
      v *= s2f(gate_b[((long)b * 128 + c) * NTOK + n]);
    } else if (c < 256) {
      int cc = c - 128;
      v = 0.f;
#pragma unroll
      for (int p = 0; p < 16; ++p)
        v = fmaf(s2f(emb_c[(((long)b * 16 + p) * 128 + cc) * NTOK + n]), ac[p], v);
      v *= s2f(gate_c[((long)b * 128 + cc) * NTOK + n]);
    } else {
      v = s2f(emb_a[((long)b * 128 + (c - 256)) * NTOK + n]);
    }
    v = 1.f / (1.f + __expf(-v));
    feat[((long)b * 384 + c) * NTOK + n] = f2s(v);
  }
}

// ======== readout: out = Wr2 @ relu(Wr1 @ feat), n-tile 32, grid (32,8) ========
__global__ __launch_bounds__(256) void r12_k(const short* __restrict__ wb,
                                             const short* __restrict__ feat,
                                             float* __restrict__ out) {
  __shared__ __align__(16) short As[256 * 64];
  __shared__ __align__(16) short Ht[32 * 256];
  __shared__ __align__(16) short Bs[32 * 64];
  const int t = threadIdx.x;
  const int n0 = blockIdx.x * 32;
  const int z = blockIdx.y;
  const int l = t & 63, w = t >> 6;
  const int lr = l & 15, lk = (l >> 4) * 8, ro = (l >> 4) * 4;
  const int bn = t & 31, kq = t >> 5;
  v4f acc[4][2];
#pragma unroll
  for (int mi = 0; mi < 4; ++mi)
#pragma unroll
    for (int ni = 0; ni < 2; ++ni) acc[mi][ni] = (v4f){0.f, 0.f, 0.f, 0.f};
  for (int k0 = 0; k0 < 384; k0 += 64) {
    __syncthreads();
#pragma unroll
    for (int c = 0; c < 8; ++c) {
      v8s pk = *(const v8s*)&wb[OB_R1 + (long)t * 384 + k0 + 8 * c];
      *(v8s*)&As[t * 64 + SWZ(t, 8 * c)] = pk;
    }
    {
      const short* fp = feat + ((long)z * 384 + k0 + kq * 8) * NTOK + n0 + bn;
      v8s pk;
#pragma unroll
      for (int j = 0; j < 8; ++j) pk[j] = fp[(long)j * NTOK];
      *(v8s*)&Bs[bn * 64 + SWZ(bn, kq * 8)] = pk;
    }
    __syncthreads();
#pragma unroll
    for (int ks = 0; ks < 2; ++ks) {
      v8s af[4], bfv[2];
#pragma unroll
      for (int mi = 0; mi < 4; ++mi) { int m = w * 64 + mi * 16 + lr; af[mi] = *(const v8s*)&As[m * 64 + SWZ(m, ks * 32 + lk)]; }
#pragma unroll
      for (int ni = 0; ni < 2; ++ni) { int nn = ni * 16 + lr; bfv[ni] = *(const v8s*)&Bs[nn * 64 + SWZ(nn, ks * 32 + lk)]; }
#pragma unroll
      for (int mi = 0; mi < 4; ++mi)
#pragma unroll
        for (int ni = 0; ni < 2; ++ni)
          acc[mi][ni] = __builtin_amdgcn_mfma_f32_16x16x32_bf16(af[mi], bfv[ni], acc[mi][ni], 0, 0, 0);
    }
  }
  __syncthreads();
#pragma unroll
  for (int mi = 0; mi < 4; ++mi)
#pragma unroll
    for (int ni = 0; ni < 2; ++ni) {
      int o = w * 64 + mi * 16 + ro, nn = ni * 16 + lr;
#pragma unroll
      for (int rp = 0; rp < 4; rp += 2)
        *(unsigned*)&Ht[nn * 256 + SWZ(nn, o + rp)] =
            pack2(fmaxf(acc[mi][ni][rp], 0.f), fmaxf(acc[mi][ni][rp + 1], 0.f));
    }
#pragma unroll
  for (int mi = 0; mi < 4; ++mi)
#pragma unroll
    for (int ni = 0; ni < 2; ++ni) acc[mi][ni] = (v4f){0.f, 0.f, 0.f, 0.f};
  for (int k0 = 0; k0 < 256; k0 += 64) {
    __syncthreads();
#pragma unroll
    for (int c = 0; c < 8; ++c) {
      v8s pk = *(const v8s*)&wb[OB_R2 + (long)t * 256 + k0 + 8 * c];
      *(v8s*)&As[t * 64 + SWZ(t, 8 * c)] = pk;
    }
    __syncthreads();
#pragma unroll
    for (int ks = 0; ks < 2; ++ks) {
      v8s af[4], bfv[2];
#pragma unroll
      for (int mi = 0; mi < 4; ++mi) { int m = w * 64 + mi * 16 + lr; af[mi] = *(const v8s*)&As[m * 64 + SWZ(m, ks * 32 + lk)]; }
#pragma unroll
      for (int ni = 0; ni < 2; ++ni) { int nn = ni * 16 + lr; bfv[ni] = *(const v8s*)&Ht[nn * 256 + SWZ(nn, k0 + ks * 32 + lk)]; }
#pragma unroll
      for (int mi = 0; mi < 4; ++mi)
#pragma unroll
        for (int ni = 0; ni < 2; ++ni)
          acc[mi][ni] = __builtin_amdgcn_mfma_f32_16x16x32_bf16(af[mi], bfv[ni], acc[mi][ni], 0, 0, 0);
    }
  }
#pragma unroll
  for (int mi = 0; mi < 4; ++mi)
#pragma unroll
    for (int ni = 0; ni < 2; ++ni)
#pragma unroll
      for (int r = 0; r < 4; ++r) {
        int o = w * 64 + mi * 16 + ro + r, nn = ni * 16 + lr;
        out[((long)z * 256 + o) * NTOK + n0 + nn] = acc[mi][ni][r];
      }
}

extern "C" void kernel_launch(void* const* d_in, const int* in_sizes, int n_in,
                              void* d_out, int out_size, void* d_ws, size_t ws_size,
                              hipStream_t stream) {
  const float* vert_a = (const float*)d_in[0];
  const float* vert_b = (const float*)d_in[1];
  const float* vert_c = (const float*)d_in[2];
  const float* wab = (const float*)d_in[11];
  const float* wac = (const float*)d_in[12];

  char* wsb = (char*)d_ws;
  size_t off = 0;
  auto alloc = [&](size_t bytes) { char* p = wsb + off; off += (bytes + 255) & ~(size_t)255; return p; };
  short* wb     = (short*)alloc((size_t)OB_END * 2);
  float* sa_b   = (float*)alloc(8192 * 4);
  float* sa_c   = (float*)alloc(8192 * 4);
  float* sb_b   = (float*)alloc(32768 * 4);
  float* sb_c   = (float*)alloc(131072 * 4);
  short* emb_a  = (short*)alloc((size_t)8 * 128 * 1024 * 2);
  short* gate_b = (short*)alloc((size_t)8 * 128 * 1024 * 2);
  short* gate_c = (short*)alloc((size_t)8 * 128 * 1024 * 2);
  short* emb_b  = (short*)alloc((size_t)32 * 128 * 1024 * 2);
  short* emb_c  = (short*)alloc((size_t)128 * 128 * 1024 * 2);
  short* feat   = (short*)alloc((size_t)8 * 384 * 1024 * 2);
  short* Tb     = (short*)alloc((size_t)32 * 128 * 1024 * 2);    // 8 MB tokenized b
  short* Tc     = (short*)alloc((size_t)128 * 64 * 1024 * 2);    // 16 MB tokenized c

  WPack P;
  const WSeg segs[10] = {
    {(const float*)d_in[3],  OB_ABC,          32768},
    {(const float*)d_in[5],  OB_ABC + 32768,  32768},
    {(const float*)d_in[6],  OB_ABC + 65536,  32768},
    {(const float*)d_in[4],  OB_A2,           16384},
    {(const float*)d_in[7],  OB_B1,           16384},
    {(const float*)d_in[8],  OB_B2,           16384},
    {(const float*)d_in[9],  OB_C1,            8192},
    {(const float*)d_in[10], OB_C2,           16384},
    {(const float*)d_in[13], OB_R1,           98304},
    {(const float*)d_in[14], OB_R2,           65536}};
  for (int i = 0; i < 10; ++i) P.seg[i] = segs[i];

  dim3 blk(256);
  phase0_k<<<2176, blk, 0, stream>>>(P, wb, vert_b, vert_c, Tb, Tc);
  phase1_k<<<1408, blk, 0, stream>>>(wb, vert_a, Tb, Tc, wab, wac,
                                     emb_a, gate_b, gate_c, emb_b, emb_c,
                                     sa_b, sa_c, sb_b, sb_c);
  feat2_k<<<dim3(16, 8), blk, 0, stream>>>(emb_b, emb_c, emb_a, gate_b, gate_c,
                                           sa_b, sb_b, sa_c, sb_c, feat);
  r12_k<<<dim3(32, 8), blk, 0, stream>>>(wb, feat, (float*)d_out);
}

// Round 6
// 195.017 us; speedup vs baseline: 5.4768x; 1.1593x over previous
//
#include <hip/hip_runtime.h>
#include <hip/hip_bf16.h>

typedef __hip_bfloat16 bf16;
typedef __attribute__((ext_vector_type(8))) short v8s;   // 8 bf16 (MFMA A/B frag)
typedef __attribute__((ext_vector_type(4))) float v4f;   // MFMA C/D frag

__device__ __forceinline__ short f2s(float v){ bf16 h = __float2bfloat16(v); return *(short*)&h; }
__device__ __forceinline__ float s2f(short s){ bf16 h = *(bf16*)&s; return __bfloat162float(h); }
__device__ __forceinline__ unsigned pack2(float a, float b){
  return (unsigned)(unsigned short)f2s(a) | ((unsigned)(unsigned short)f2s(b) << 16);
}
__device__ __forceinline__ int SWZ(int row, int idx){ return idx ^ ((row & 7) << 3); }

#define NTOK 1024

enum : int {
  OB_ABC = 0,                 // [384][256]: rows 0-127 Wa1, 128-255 Wgb, 256-383 Wgc
  OB_A2  = 98304,             // [128][128]
  OB_B1  = 114688,            // [128][128]
  OB_B2  = 131072,            // [128][128]
  OB_C1  = 147456,            // [128][64]
  OB_C2  = 155648,            // [128][128]
  OB_R1  = 172032,            // [256][384]
  OB_R2  = 270336,            // [256][256]
  OB_END = 335872
};

struct WSeg { const float* src; int off; int n; };
struct WPack { WSeg seg[10]; };

// ======== phase0: tokenize (coalesced transpose via LDS) + weight convert ========
template<int R, int HW, int K>
__device__ __forceinline__ void tok_dev(const float* __restrict__ V, short* __restrict__ T,
                                        int b, int k, char* smem) {
  short* L = (short*)smem;  // [R*R][1024]
  const int t = threadIdx.x;
  const float4* src = (const float4*)(V + ((long)b * K + k) * HW * HW);
  constexpr int NF4 = HW * HW / 4;
  constexpr int P2 = R * R;
  for (int idx = t; idx < NF4; idx += 256) {
    int y = idx / (HW / 4);
    int x4 = (idx % (HW / 4)) * 4;
    float4 v = src[idx];
    float vv[4] = {v.x, v.y, v.z, v.w};
    int pb = (y % R) * R, ny = (y / R) * 32;
#pragma unroll
    for (int j = 0; j < 4; ++j) {
      int x = x4 + j;
      L[(pb + (x % R)) * 1024 + ny + x / R] = f2s(vv[j]);
    }
  }
  __syncthreads();
  for (int idx = t; idx < P2 * 128; idx += 256) {
    int p = idx >> 7, c8 = (idx & 127) * 8;
    *(v8s*)&T[((long)(b * P2 + p) * K + k) * 1024 + c8] = *(const v8s*)&L[p * 1024 + c8];
  }
}

__global__ __launch_bounds__(256) void phase0_k(WPack P, short* __restrict__ wb,
                                                const float* __restrict__ vb,
                                                const float* __restrict__ vc,
                                                short* __restrict__ Tb,
                                                short* __restrict__ Tc) {
  __shared__ __align__(16) char smem[32768];
  int bid = blockIdx.x;
  if (bid < 512) {
    tok_dev<4, 128, 64>(vc, Tc, bid >> 6, bid & 63, smem);
  } else if (bid < 1536) {
    int i = bid - 512;
    tok_dev<2, 64, 128>(vb, Tb, i >> 7, i & 127, smem);
  } else {
    int i = bid - 1536;
    WSeg s = P.seg[i / 64];
    for (int j = (i & 63) * 256 + threadIdx.x; j < s.n; j += 16384)
      wb[s.off + j] = f2s(s.src[j]);
  }
}

// ======== phase1 device: a-path ========
__device__ __forceinline__ void mlp_a_dev(char* smem, const short* __restrict__ wb,
                                          const float* __restrict__ va,
                                          const float* __restrict__ wab,
                                          const float* __restrict__ wac,
                                          short* __restrict__ emb_a,
                                          short* __restrict__ gate_b,
                                          short* __restrict__ gate_c,
                                          float* __restrict__ sa_b,
                                          float* __restrict__ sa_c,
                                          int nx, int z) {
  short* Bs = (short*)smem;              // [64 n][256 k]
  short* As = (short*)(smem + 32768);    // [128 m][64 k]
  short* Ht = (short*)(smem + 49152);    // [64 n][128 h]
  float* sbl = (float*)(smem + 65536);
  float* scl = (float*)(smem + 65792);
  float* wl  = (float*)(smem + 66048);
  float* wcl = (float*)(smem + 66560);
  const int t = threadIdx.x;
  const int n0 = nx * 64;
  const int l = t & 63, w = t >> 6;
  const int lr = l & 15, lk = (l >> 4) * 8, ro = (l >> 4) * 4;
  if (t < 128) { wl[t] = wab[t]; wcl[t] = wac[t]; }
  if (t < 64) { sbl[t] = 0.f; scl[t] = 0.f; }
  {
    const int n = t & 63, kq = t >> 6;
    for (int it = 0; it < 8; ++it) {
      int k0 = (kq + 4 * it) * 8;
      v8s pk;
#pragma unroll
      for (int j = 0; j < 8; ++j) pk[j] = f2s(va[((long)z * 256 + k0 + j) * NTOK + n0 + n]);
      *(v8s*)&Bs[n * 256 + SWZ(n, k0)] = pk;
    }
  }
  const int ar = t >> 1, akh = (t & 1) * 32;
  v4f acc[2][4];
  for (int p = 0; p < 3; ++p) {
#pragma unroll
    for (int mi = 0; mi < 2; ++mi)
#pragma unroll
      for (int ni = 0; ni < 4; ++ni) acc[mi][ni] = (v4f){0.f, 0.f, 0.f, 0.f};
    for (int k0 = 0; k0 < 256; k0 += 64) {
      __syncthreads();
#pragma unroll
      for (int c = 0; c < 4; ++c) {
        v8s pk = *(const v8s*)&wb[OB_ABC + (long)(p * 128 + ar) * 256 + k0 + akh + 8 * c];
        *(v8s*)&As[ar * 64 + SWZ(ar, akh + 8 * c)] = pk;
      }
      __syncthreads();
#pragma unroll
      for (int ks = 0; ks < 2; ++ks) {
        v8s af[2], bfv[4];
#pragma unroll
        for (int mi = 0; mi < 2; ++mi) { int m = w * 32 + mi * 16 + lr; af[mi] = *(const v8s*)&As[m * 64 + SWZ(m, ks * 32 + lk)]; }
#pragma unroll
        for (int ni = 0; ni < 4; ++ni) { int nn = ni * 16 + lr; bfv[ni] = *(const v8s*)&Bs[nn * 256 + SWZ(nn, k0 + ks * 32 + lk)]; }
#pragma unroll
        for (int mi = 0; mi < 2; ++mi)
#pragma unroll
          for (int ni = 0; ni < 4; ++ni)
            acc[mi][ni] = __builtin_amdgcn_mfma_f32_16x16x32_bf16(af[mi], bfv[ni], acc[mi][ni], 0, 0, 0);
      }
    }
    if (p == 0) {
#pragma unroll
      for (int mi = 0; mi < 2; ++mi)
#pragma unroll
        for (int ni = 0; ni < 4; ++ni) {
          int o = w * 32 + mi * 16 + ro, nn = ni * 16 + lr;
#pragma unroll
          for (int rp = 0; rp < 4; rp += 2)
            *(unsigned*)&Ht[nn * 128 + SWZ(nn, o + rp)] =
                pack2(fmaxf(acc[mi][ni][rp], 0.f), fmaxf(acc[mi][ni][rp + 1], 0.f));
        }
    } else {
      short* g = (p == 1) ? gate_b : gate_c;
#pragma unroll
      for (int mi = 0; mi < 2; ++mi)
#pragma unroll
        for (int ni = 0; ni < 4; ++ni)
#pragma unroll
          for (int r = 0; r < 4; ++r) {
            int o = w * 32 + mi * 16 + ro + r, nn = ni * 16 + lr;
            g[((long)z * 128 + o) * NTOK + n0 + nn] = f2s(1.f / (1.f + __expf(acc[mi][ni][r])));
          }
    }
  }
  __syncthreads();
#pragma unroll
  for (int mi = 0; mi < 2; ++mi)
#pragma unroll
    for (int ni = 0; ni < 4; ++ni) acc[mi][ni] = (v4f){0.f, 0.f, 0.f, 0.f};
  for (int k0 = 0; k0 < 128; k0 += 64) {
    __syncthreads();
#pragma unroll
    for (int c = 0; c < 4; ++c) {
      v8s pk = *(const v8s*)&wb[OB_A2 + (long)ar * 128 + k0 + akh + 8 * c];
      *(v8s*)&As[ar * 64 + SWZ(ar, akh + 8 * c)] = pk;
    }
    __syncthreads();
#pragma unroll
    for (int ks = 0; ks < 2; ++ks) {
      v8s af[2], bfv[4];
#pragma unroll
      for (int mi = 0; mi < 2; ++mi) { int m = w * 32 + mi * 16 + lr; af[mi] = *(const v8s*)&As[m * 64 + SWZ(m, ks * 32 + lk)]; }
#pragma unroll
      for (int ni = 0; ni < 4; ++ni) { int nn = ni * 16 + lr; bfv[ni] = *(const v8s*)&Ht[nn * 128 + SWZ(nn, k0 + ks * 32 + lk)]; }
#pragma unroll
      for (int mi = 0; mi < 2; ++mi)
#pragma unroll
        for (int ni = 0; ni < 4; ++ni)
          acc[mi][ni] = __builtin_amdgcn_mfma_f32_16x16x32_bf16(af[mi], bfv[ni], acc[mi][ni], 0, 0, 0);
    }
  }
#pragma unroll
  for (int ni = 0; ni < 4; ++ni) {
    int nn = ni * 16 + lr;
    float pb = 0.f, pc = 0.f;
#pragma unroll
    for (int mi = 0; mi < 2; ++mi)
#pragma unroll
      for (int r = 0; r < 4; ++r) {
        int o = w * 32 + mi * 16 + ro + r;
        float v = acc[mi][ni][r];
        emb_a[((long)z * 128 + o) * NTOK + n0 + nn] = f2s(v);
        pb = fmaf(wl[o], v, pb);
        pc = fmaf(wcl[o], v, pc);
      }
    atomicAdd(&sbl[nn], pb);
    atomicAdd(&scl[nn], pc);
  }
  __syncthreads();
  if (t < 64) {
    sa_b[(long)z * NTOK + n0 + t] = sbl[t];
    sa_c[(long)z * NTOK + n0 + t] = scl[t];
  }
}

// ======== phase1 device: token MLP (2 layers), LDS-transposed vectorized E store ========
template<int K1>
__device__ __forceinline__ void mlp2_dev(char* smem, const short* __restrict__ w1,
                                         const short* __restrict__ w2,
                                         const short* __restrict__ T,
                                         const float* __restrict__ wvec,
                                         short* __restrict__ E,
                                         float* __restrict__ SB,
                                         int nx, int z) {
  short* Bs = (short*)smem;              // [128 n][64 k]
  short* As = (short*)(smem + 16384);    // [128 m][64 k]
  short* Ht = (short*)(smem + 32768);    // [128 n][128 h] ; reused as Et [128 o][128 n]
  float* scl = (float*)(smem + 65536);
  float* wl  = (float*)(smem + 66048);
  const int t = threadIdx.x;
  const int n0 = nx * 128;
  const int l = t & 63, w = t >> 6;
  const int wr = w >> 1, wc = w & 1;
  const int lr = l & 15, lk = (l >> 4) * 8, ro = (l >> 4) * 4;
  if (t < 128) { wl[t] = wvec[t]; scl[t] = 0.f; }
  const int ar = t >> 1, akh = (t & 1) * 32;
  const int bn = t & 127, bkh = (t >> 7) * 32;
  const short* xz = T + (long)z * K1 * NTOK;
  v4f acc[4][4];
#pragma unroll
  for (int mi = 0; mi < 4; ++mi)
#pragma unroll
    for (int ni = 0; ni < 4; ++ni) acc[mi][ni] = (v4f){0.f, 0.f, 0.f, 0.f};
  for (int k0 = 0; k0 < K1; k0 += 64) {
    __syncthreads();
#pragma unroll
    for (int c = 0; c < 4; ++c) {
      v8s pk = *(const v8s*)&w1[(long)ar * K1 + k0 + akh + 8 * c];
      *(v8s*)&As[ar * 64 + SWZ(ar, akh + 8 * c)] = pk;
    }
    {
      const short* xcol = xz + (long)(k0 + bkh) * NTOK + n0 + bn;
#pragma unroll
      for (int c = 0; c < 4; ++c) {
        v8s pk;
#pragma unroll
        for (int j = 0; j < 8; ++j) pk[j] = xcol[(long)(8 * c + j) * NTOK];
        *(v8s*)&Bs[bn * 64 + SWZ(bn, bkh + 8 * c)] = pk;
      }
    }
    __syncthreads();
#pragma unroll
    for (int ks = 0; ks < 2; ++ks) {
      v8s af[4], bfv[4];
#pragma unroll
      for (int mi = 0; mi < 4; ++mi) { int m = wr * 64 + mi * 16 + lr; af[mi] = *(const v8s*)&As[m * 64 + SWZ(m, ks * 32 + lk)]; }
#pragma unroll
      for (int ni = 0; ni < 4; ++ni) { int nn = wc * 64 + ni * 16 + lr; bfv[ni] = *(const v8s*)&Bs[nn * 64 + SWZ(nn, ks * 32 + lk)]; }
#pragma unroll
      for (int mi = 0; mi < 4; ++mi)
#pragma unroll
        for (int ni = 0; ni < 4; ++ni)
          acc[mi][ni] = __builtin_amdgcn_mfma_f32_16x16x32_bf16(af[mi], bfv[ni], acc[mi][ni], 0, 0, 0);
    }
  }
  __syncthreads();
#pragma unroll
  for (int mi = 0; mi < 4; ++mi)
#pragma unroll
    for (int ni = 0; ni < 4; ++ni) {
      int o = wr * 64 + mi * 16 + ro, nn = wc * 64 + ni * 16 + lr;
#pragma unroll
      for (int rp = 0; rp < 4; rp += 2)
        *(unsigned*)&Ht[nn * 128 + SWZ(nn, o + rp)] =
            pack2(fmaxf(acc[mi][ni][rp], 0.f), fmaxf(acc[mi][ni][rp + 1], 0.f));
    }
#pragma unroll
  for (int mi = 0; mi < 4; ++mi)
#pragma unroll
    for (int ni = 0; ni < 4; ++ni) acc[mi][ni] = (v4f){0.f, 0.f, 0.f, 0.f};
  for (int k0 = 0; k0 < 128; k0 += 64) {
    __syncthreads();
#pragma unroll
    for (int c = 0; c < 4; ++c) {
      v8s pk = *(const v8s*)&w2[(long)ar * 128 + k0 + akh + 8 * c];
      *(v8s*)&As[ar * 64 + SWZ(ar, akh + 8 * c)] = pk;
    }
    __syncthreads();
#pragma unroll
    for (int ks = 0; ks < 2; ++ks) {
      v8s af[4], bfv[4];
#pragma unroll
      for (int mi = 0; mi < 4; ++mi) { int m = wr * 64 + mi * 16 + lr; af[mi] = *(const v8s*)&As[m * 64 + SWZ(m, ks * 32 + lk)]; }
#pragma unroll
      for (int ni = 0; ni < 4; ++ni) { int nn = wc * 64 + ni * 16 + lr; bfv[ni] = *(const v8s*)&Ht[nn * 128 + SWZ(nn, k0 + ks * 32 + lk)]; }
#pragma unroll
      for (int mi = 0; mi < 4; ++mi)
#pragma unroll
        for (int ni = 0; ni < 4; ++ni)
          acc[mi][ni] = __builtin_amdgcn_mfma_f32_16x16x32_bf16(af[mi], bfv[ni], acc[mi][ni], 0, 0, 0);
    }
  }
  // score partials (keep f32 acc before Et rounding)
#pragma unroll
  for (int ni = 0; ni < 4; ++ni) {
    int nn = wc * 64 + ni * 16 + lr;
    float pb = 0.f;
#pragma unroll
    for (int mi = 0; mi < 4; ++mi)
#pragma unroll
      for (int r = 0; r < 4; ++r) pb = fmaf(wl[wr * 64 + mi * 16 + ro + r], acc[mi][ni][r], pb);
    atomicAdd(&scl[nn], pb);
  }
  __syncthreads();   // Ht reads + scl adds done
  // Et = E^T tile [o][n] in LDS (reuse Ht), then vectorized global store
  short* Et = Ht;
#pragma unroll
  for (int mi = 0; mi < 4; ++mi)
#pragma unroll
    for (int ni = 0; ni < 4; ++ni)
#pragma unroll
      for (int r = 0; r < 4; ++r) {
        int o = wr * 64 + mi * 16 + ro + r, nn = wc * 64 + ni * 16 + lr;
        Et[o * 128 + SWZ(o, nn)] = f2s(acc[mi][ni][r]);
      }
  __syncthreads();
#pragma unroll
  for (int it = 0; it < 8; ++it) {
    int chunk = it * 256 + t;
    int o = chunk >> 4, n8 = (chunk & 15) * 8;
    v8s pk = *(const v8s*)&Et[o * 128 + SWZ(o, n8)];
    *(v8s*)&E[((long)z * 128 + o) * NTOK + n0 + n8] = pk;
  }
  if (t < 128) SB[(long)z * NTOK + n0 + t] = scl[t];
}

// ======== phase1: mlp2_c [0,1024) + mlp2_b [1024,1280) + mlp_a [1280,1408) ========
__global__ __launch_bounds__(256) void phase1_k(const short* __restrict__ wb,
                                                const float* __restrict__ va,
                                                const short* __restrict__ Tb,
                                                const short* __restrict__ Tc,
                                                const float* __restrict__ wab,
                                                const float* __restrict__ wac,
                                                short* emb_a, short* gate_b, short* gate_c,
                                                short* emb_b, short* emb_c,
                                                float* sa_b, float* sa_c,
                                                float* sb_b, float* sb_c) {
  __shared__ __align__(16) char smem[67584];
  int bid = blockIdx.x;
  if (bid < 1024) {
    mlp2_dev<64>(smem, wb + OB_C1, wb + OB_C2, Tc, wac + 128, emb_c, sb_c, bid & 7, bid >> 3);
  } else if (bid < 1280) {
    int i = bid - 1024;
    mlp2_dev<128>(smem, wb + OB_B1, wb + OB_B2, Tb, wab + 128, emb_b, sb_b, i & 7, i >> 3);
  } else {
    int i = bid - 1280;
    mlp_a_dev(smem, wb, va, wab, wac, emb_a, gate_b, gate_c, sa_b, sa_c, i & 15, i >> 4);
  }
}

// ======== attn precompute: softmax over p of relu(sa+sb) ========
__global__ __launch_bounds__(256) void attn_k(const float* __restrict__ sa_b,
                                              const float* __restrict__ sb_b,
                                              const float* __restrict__ sa_c,
                                              const float* __restrict__ sb_c,
                                              float* __restrict__ attn_b,
                                              float* __restrict__ attn_c) {
  int i = blockIdx.x * 256 + threadIdx.x;  // 8192 = b*1024+n
  int b = i >> 10, n = i & 1023;
  {
    float sa = sa_b[i], m = 0.f, s[4], den = 0.f;
#pragma unroll
    for (int p = 0; p < 4; ++p) { s[p] = fmaxf(sa + sb_b[((long)b * 4 + p) * NTOK + n], 0.f); m = fmaxf(m, s[p]); }
#pragma unroll
    for (int p = 0; p < 4; ++p) { s[p] = __expf(s[p] - m); den += s[p]; }
    float r = 1.f / den;
#pragma unroll
    for (int p = 0; p < 4; ++p) attn_b[((long)b * 4 + p) * NTOK + n] = s[p] * r;
  }
  {
    float sa = sa_c[i], m = 0.f, s[16], den = 0.f;
#pragma unroll
    for (int p = 0; p < 16; ++p) { s[p] = fmaxf(sa + sb_c[((long)b * 16 + p) * NTOK + n], 0.f); m = fmaxf(m, s[p]); }
#pragma unroll
    for (int p = 0; p < 16; ++p) { s[p] = __expf(s[p] - m); den += s[p]; }
    float r = 1.f / den;
#pragma unroll
    for (int p = 0; p < 16; ++p) attn_c[((long)b * 16 + p) * NTOK + n] = s[p] * r;
  }
}

// ======== feat = sigmoid([agg_b*gate_b ; agg_c*gate_c ; emb_a]), n-vectorized ========
// grid (192 c-pairs, 8 b); thread: c = bx*2 + (t>>7), n0 = (t&127)*8.
__global__ __launch_bounds__(256) void feat3_k(const short* __restrict__ emb_b,
                                               const short* __restrict__ emb_c,
                                               const short* __restrict__ emb_a,
                                               const short* __restrict__ gate_b,
                                               const short* __restrict__ gate_c,
                                               const float* __restrict__ attn_b,
                                               const float* __restrict__ attn_c,
                                               short* __restrict__ feat) {
  const int t = threadIdx.x;
  const int c = blockIdx.x * 2 + (t >> 7);
  const int n0 = (t & 127) * 8;
  const int b = blockIdx.y;
  float acc[8];
  if (c < 256) {
#pragma unroll
    for (int j = 0; j < 8; ++j) acc[j] = 0.f;
    if (c < 128) {
#pragma unroll
      for (int p = 0; p < 4; ++p) {
        v8s e = *(const v8s*)&emb_b[(((long)(b * 4 + p)) * 128 + c) * NTOK + n0];
        const float* ap = attn_b + ((long)(b * 4 + p)) * NTOK + n0;
        float4 a0 = *(const float4*)ap, a1 = *(const float4*)(ap + 4);
        acc[0] = fmaf(s2f(e[0]), a0.x, acc[0]); acc[1] = fmaf(s2f(e[1]), a0.y, acc[1]);
        acc[2] = fmaf(s2f(e[2]), a0.z, acc[2]); acc[3] = fmaf(s2f(e[3]), a0.w, acc[3]);
        acc[4] = fmaf(s2f(e[4]), a1.x, acc[4]); acc[5] = fmaf(s2f(e[5]), a1.y, acc[5]);
        acc[6] = fmaf(s2f(e[6]), a1.z, acc[6]); acc[7] = fmaf(s2f(e[7]), a1.w, acc[7]);
      }
      v8s g = *(const v8s*)&gate_b[((long)(b * 128 + c)) * NTOK + n0];
#pragma unroll
      for (int j = 0; j < 8; ++j) acc[j] *= s2f(g[j]);
    } else {
      int cc = c - 128;
#pragma unroll
      for (int p = 0; p < 16; ++p) {
        v8s e = *(const v8s*)&emb_c[(((long)(b * 16 + p)) * 128 + cc) * NTOK + n0];
        const float* ap = attn_c + ((long)(b * 16 + p)) * NTOK + n0;
        float4 a0 = *(const float4*)ap, a1 = *(const float4*)(ap + 4);
        acc[0] = fmaf(s2f(e[0]), a0.x, acc[0]); acc[1] = fmaf(s2f(e[1]), a0.y, acc[1]);
        acc[2] = fmaf(s2f(e[2]), a0.z, acc[2]); acc[3] = fmaf(s2f(e[3]), a0.w, acc[3]);
        acc[4] = fmaf(s2f(e[4]), a1.x, acc[4]); acc[5] = fmaf(s2f(e[5]), a1.y, acc[5]);
        acc[6] = fmaf(s2f(e[6]), a1.z, acc[6]); acc[7] = fmaf(s2f(e[7]), a1.w, acc[7]);
      }
      v8s g = *(const v8s*)&gate_c[((long)(b * 128 + cc)) * NTOK + n0];
#pragma unroll
      for (int j = 0; j < 8; ++j) acc[j] *= s2f(g[j]);
    }
  } else {
    v8s e = *(const v8s*)&emb_a[((long)(b * 128 + (c - 256))) * NTOK + n0];
#pragma unroll
    for (int j = 0; j < 8; ++j) acc[j] = s2f(e[j]);
  }
  v8s o;
#pragma unroll
  for (int j = 0; j < 8; ++j) o[j] = f2s(1.f / (1.f + __expf(-acc[j])));
  *(v8s*)&feat[((long)(b * 384 + c)) * NTOK + n0] = o;
}

// ======== readout: out = Wr2 @ relu(Wr1 @ feat), padded-LDS f32 store ========
__global__ __launch_bounds__(256) void r12_k(const short* __restrict__ wb,
                                             const short* __restrict__ feat,
                                             float* __restrict__ out) {
  __shared__ __align__(16) char smem[53248];
  short* As = (short*)smem;              // [256][64]
  short* Ht = (short*)(smem + 32768);    // [32 n][256 h]
  short* Bs = (short*)(smem + 49152);    // [32 n][64 k]
  float* Ot = (float*)smem;              // [256 o][36 n] (36864 B, reused after k-loops)
  const int t = threadIdx.x;
  const int n0 = blockIdx.x * 32;
  const int z = blockIdx.y;
  const int l = t & 63, w = t >> 6;
  const int lr = l & 15, lk = (l >> 4) * 8, ro = (l >> 4) * 4;
  const int bn = t & 31, kq = t >> 5;
  v4f acc[4][2];
#pragma unroll
  for (int mi = 0; mi < 4; ++mi)
#pragma unroll
    for (int ni = 0; ni < 2; ++ni) acc[mi][ni] = (v4f){0.f, 0.f, 0.f, 0.f};
  for (int k0 = 0; k0 < 384; k0 += 64) {
    __syncthreads();
#pragma unroll
    for (int c = 0; c < 8; ++c) {
      v8s pk = *(const v8s*)&wb[OB_R1 + (long)t * 384 + k0 + 8 * c];
      *(v8s*)&As[t * 64 + SWZ(t, 8 * c)] = pk;
    }
    {
      const short* fp = feat + ((long)z * 384 + k0 + kq * 8) * NTOK + n0 + bn;
      v8s pk;
#pragma unroll
      for (int j = 0; j < 8; ++j) pk[j] = fp[(long)j * NTOK];
      *(v8s*)&Bs[bn * 64 + SWZ(bn, kq * 8)] = pk;
    }
    __syncthreads();
#pragma unroll
    for (int ks = 0; ks < 2; ++ks) {
      v8s af[4], bfv[2];
#pragma unroll
      for (int mi = 0; mi < 4; ++mi) { int m = w * 64 + mi * 16 + lr; af[mi] = *(const v8s*)&As[m * 64 + SWZ(m, ks * 32 + lk)]; }
#pragma unroll
      for (int ni = 0; ni < 2; ++ni) { int nn = ni * 16 + lr; bfv[ni] = *(const v8s*)&Bs[nn * 64 + SWZ(nn, ks * 32 + lk)]; }
#pragma unroll
      for (int mi = 0; mi < 4; ++mi)
#pragma unroll
        for (int ni = 0; ni < 2; ++ni)
          acc[mi][ni] = __builtin_amdgcn_mfma_f32_16x16x32_bf16(af[mi], bfv[ni], acc[mi][ni], 0, 0, 0);
    }
  }
  __syncthreads();
#pragma unroll
  for (int mi = 0; mi < 4; ++mi)
#pragma unroll
    for (int ni = 0; ni < 2; ++ni) {
      int o = w * 64 + mi * 16 + ro, nn = ni * 16 + lr;
#pragma unroll
      for (int rp = 0; rp < 4; rp += 2)
        *(unsigned*)&Ht[nn * 256 + SWZ(nn, o + rp)] =
            pack2(fmaxf(acc[mi][ni][rp], 0.f), fmaxf(acc[mi][ni][rp + 1], 0.f));
    }
#pragma unroll
  for (int mi = 0; mi < 4; ++mi)
#pragma unroll
    for (int ni = 0; ni < 2; ++ni) acc[mi][ni] = (v4f){0.f, 0.f, 0.f, 0.f};
  for (int k0 = 0; k0 < 256; k0 += 64) {
    __syncthreads();
#pragma unroll
    for (int c = 0; c < 8; ++c) {
      v8s pk = *(const v8s*)&wb[OB_R2 + (long)t * 256 + k0 + 8 * c];
      *(v8s*)&As[t * 64 + SWZ(t, 8 * c)] = pk;
    }
    __syncthreads();
#pragma unroll
    for (int ks = 0; ks < 2; ++ks) {
      v8s af[4], bfv[2];
#pragma unroll
      for (int mi = 0; mi < 4; ++mi) { int m = w * 64 + mi * 16 + lr; af[mi] = *(const v8s*)&As[m * 64 + SWZ(m, ks * 32 + lk)]; }
#pragma unroll
      for (int ni = 0; ni < 2; ++ni) { int nn = ni * 16 + lr; bfv[ni] = *(const v8s*)&Ht[nn * 256 + SWZ(nn, k0 + ks * 32 + lk)]; }
#pragma unroll
      for (int mi = 0; mi < 4; ++mi)
#pragma unroll
        for (int ni = 0; ni < 2; ++ni)
          acc[mi][ni] = __builtin_amdgcn_mfma_f32_16x16x32_bf16(af[mi], bfv[ni], acc[mi][ni], 0, 0, 0);
    }
  }
  __syncthreads();   // As/Ht dead; reuse as Ot
#pragma unroll
  for (int mi = 0; mi < 4; ++mi)
#pragma unroll
    for (int ni = 0; ni < 2; ++ni)
#pragma unroll
      for (int r = 0; r < 4; ++r) {
        int o = w * 64 + mi * 16 + ro + r, nn = ni * 16 + lr;
        Ot[o * 36 + nn] = acc[mi][ni][r];
      }
  __syncthreads();
#pragma unroll
  for (int it = 0; it < 8; ++it) {
    int chunk = it * 256 + t;
    int o = chunk >> 3, n4 = (chunk & 7) * 4;
    float4 v = *(const float4*)&Ot[o * 36 + n4];
    *(float4*)&out[((long)z * 256 + o) * NTOK + n0 + n4] = v;
  }
}

extern "C" void kernel_launch(void* const* d_in, const int* in_sizes, int n_in,
                              void* d_out, int out_size, void* d_ws, size_t ws_size,
                              hipStream_t stream) {
  const float* vert_a = (const float*)d_in[0];
  const float* vert_b = (const float*)d_in[1];
  const float* vert_c = (const float*)d_in[2];
  const float* wab = (const float*)d_in[11];
  const float* wac = (const float*)d_in[12];

  char* wsb = (char*)d_ws;
  size_t off = 0;
  auto alloc = [&](size_t bytes) { char* p = wsb + off; off += (bytes + 255) & ~(size_t)255; return p; };
  short* wb     = (short*)alloc((size_t)OB_END * 2);
  float* sa_b   = (float*)alloc(8192 * 4);
  float* sa_c   = (float*)alloc(8192 * 4);
  float* sb_b   = (float*)alloc(32768 * 4);
  float* sb_c   = (float*)alloc(131072 * 4);
  float* attn_b = (float*)alloc(32768 * 4);
  float* attn_c = (float*)alloc(131072 * 4);
  short* emb_a  = (short*)alloc((size_t)8 * 128 * 1024 * 2);
  short* gate_b = (short*)alloc((size_t)8 * 128 * 1024 * 2);
  short* gate_c = (short*)alloc((size_t)8 * 128 * 1024 * 2);
  short* emb_b  = (short*)alloc((size_t)32 * 128 * 1024 * 2);
  short* emb_c  = (short*)alloc((size_t)128 * 128 * 1024 * 2);
  short* feat   = (short*)alloc((size_t)8 * 384 * 1024 * 2);
  short* Tb     = (short*)alloc((size_t)32 * 128 * 1024 * 2);
  short* Tc     = (short*)alloc((size_t)128 * 64 * 1024 * 2);

  WPack P;
  const WSeg segs[10] = {
    {(const float*)d_in[3],  OB_ABC,          32768},
    {(const float*)d_in[5],  OB_ABC + 32768,  32768},
    {(const float*)d_in[6],  OB_ABC + 65536,  32768},
    {(const float*)d_in[4],  OB_A2,           16384},
    {(const float*)d_in[7],  OB_B1,           16384},
    {(const float*)d_in[8],  OB_B2,           16384},
    {(const float*)d_in[9],  OB_C1,            8192},
    {(const float*)d_in[10], OB_C2,           16384},
    {(const float*)d_in[13], OB_R1,           98304},
    {(const float*)d_in[14], OB_R2,           65536}};
  for (int i = 0; i < 10; ++i) P.seg[i] = segs[i];

  dim3 blk(256);
  phase0_k<<<2176, blk, 0, stream>>>(P, wb, vert_b, vert_c, Tb, Tc);
  phase1_k<<<1408, blk, 0, stream>>>(wb, vert_a, Tb, Tc, wab, wac,
                                     emb_a, gate_b, gate_c, emb_b, emb_c,
                                     sa_b, sa_c, sb_b, sb_c);
  attn_k<<<32, blk, 0, stream>>>(sa_b, sb_b, sa_c, sb_c, attn_b, attn_c);
  feat3_k<<<dim3(192, 8), blk, 0, stream>>>(emb_b, emb_c, emb_a, gate_b, gate_c,
                                            attn_b, attn_c, feat);
  r12_k<<<dim3(32, 8), blk, 0, stream>>>(wb, feat, (float*)d_out);
}